// Round 17
// baseline (141.507 us; speedup 1.0000x reference)
//
#include <hip/hip_runtime.h>
#include <hip/hip_bf16.h>
#include <stdint.h>

#define B_ 4
#define P_ 256
#define S_ 4096
#define D_ 1024
#define H_ 16
#define HD_ 64

typedef __attribute__((ext_vector_type(8))) short short8;
typedef __attribute__((ext_vector_type(4))) short short4v;
typedef __attribute__((ext_vector_type(2))) short short2v;
typedef __attribute__((ext_vector_type(4))) float f32x4;

__device__ __forceinline__ float b2f(short s) {
  return __uint_as_float(((unsigned)(unsigned short)s) << 16);
}
__device__ __forceinline__ short f2bf(float f) {
  unsigned u = __float_as_uint(f);
  unsigned r = (u + 0x7fffu + ((u >> 16) & 1u)) >> 16;
  return (short)(unsigned short)r;
}

// ---------------------------------------------------------------------------
// prep2: wq,wv,wo -> bf16; wk -> bf16 TRANSPOSED (wkT); LN(pe) -> qx
// ---------------------------------------------------------------------------
__global__ __launch_bounds__(256) void prep2_kernel(
    const float* __restrict__ pe,
    const float* __restrict__ gamma, const float* __restrict__ beta,
    const float* __restrict__ wq, const float* __restrict__ wk,
    const float* __restrict__ wv, const float* __restrict__ wo,
    short* __restrict__ wqb, short* __restrict__ wvb, short* __restrict__ wob,
    short* __restrict__ wkT, short* __restrict__ qx)
{
  const int bid = blockIdx.x;
  const int tid = threadIdx.x;
  if (bid < 1536) {
    const int wi = bid >> 9;
    const size_t base = (size_t)(bid & 511) * 2048 + (size_t)tid * 8;
    const float* src; short* dst;
    if (wi == 0)      { src = wq; dst = wqb; }
    else if (wi == 1) { src = wv; dst = wvb; }
    else              { src = wo; dst = wob; }
    const float4 f0 = *(const float4*)(src + base);
    const float4 f1 = *(const float4*)(src + base + 4);
    short8 o;
    o[0] = f2bf(f0.x); o[1] = f2bf(f0.y); o[2] = f2bf(f0.z); o[3] = f2bf(f0.w);
    o[4] = f2bf(f1.x); o[5] = f2bf(f1.y); o[6] = f2bf(f1.z); o[7] = f2bf(f1.w);
    *(short8*)(dst + base) = o;
  } else if (bid < 1600) {
    __shared__ short Ts[128][132];
    const int t = bid - 1536;
    const int ti = t >> 3, tj = t & 7;
    #pragma unroll
    for (int j = 0; j < 16; ++j) {
      const int r = j * 8 + (tid >> 5);
      const int c4 = (tid & 31) * 4;
      const float4 v = *(const float4*)(wk + (size_t)(ti * 128 + r) * D_ + tj * 128 + c4);
      short4v o;
      o[0] = f2bf(v.x); o[1] = f2bf(v.y); o[2] = f2bf(v.z); o[3] = f2bf(v.w);
      *(short4v*)(&Ts[r][c4]) = o;
    }
    __syncthreads();
    #pragma unroll
    for (int j = 0; j < 16; ++j) {
      const int c = j * 8 + (tid >> 5);
      const int r4 = (tid & 31) * 4;
      short4v o;
      o[0] = Ts[r4 + 0][c]; o[1] = Ts[r4 + 1][c];
      o[2] = Ts[r4 + 2][c]; o[3] = Ts[r4 + 3][c];
      *(short4v*)(wkT + (size_t)(tj * 128 + c) * D_ + ti * 128 + r4) = o;
    }
  } else {
    const int row = bid - 1600;
    const int c = tid * 4;
    const float4 x = *(const float4*)(pe + (size_t)row * D_ + c);
    float s1 = x.x + x.y + x.z + x.w;
    float s2 = x.x * x.x + x.y * x.y + x.z * x.z + x.w * x.w;
    #pragma unroll
    for (int off = 32; off >= 1; off >>= 1) {
      s1 += __shfl_xor(s1, off, 64);
      s2 += __shfl_xor(s2, off, 64);
    }
    __shared__ float red[8];
    const int wid = tid >> 6, lane = tid & 63;
    if (lane == 0) { red[wid] = s1; red[4 + wid] = s2; }
    __syncthreads();
    s1 = red[0] + red[1] + red[2] + red[3];
    s2 = red[4] + red[5] + red[6] + red[7];
    const float mu = s1 * (1.0f / D_);
    const float var = s2 * (1.0f / D_) - mu * mu;
    const float rs = rsqrtf(var + 1e-5f);
    const float4 g = *(const float4*)(gamma + c);
    const float4 bt = *(const float4*)(beta + c);
    short4v o;
    o[0] = f2bf((x.x - mu) * rs * g.x + bt.x);
    o[1] = f2bf((x.y - mu) * rs * g.y + bt.y);
    o[2] = f2bf((x.z - mu) * rs * g.z + bt.z);
    o[3] = f2bf((x.w - mu) * rs * g.w + bt.w);
    *(short4v*)(qx + (size_t)row * D_ + c) = o;
  }
}

// ---------------------------------------------------------------------------
// 64x64-tile GEMM core (R10 single-buffer, measured-best)
// ---------------------------------------------------------------------------
__device__ __forceinline__ void gemm64_core(
    const short* __restrict__ A, const short* __restrict__ W,
    int mt, int nt, int Kd, int lda, int ldb,
    f32x4 acc[2][2], short* As, short* Bs)
{
  const int tid = threadIdx.x;
  const int w = tid >> 6, l = tid & 63;
  const int wr = w >> 1, wc = w & 1;
  const int lr = l & 15, lk = l >> 4;
  (void)l; (void)w;

  for (int kt = 0; kt < Kd; kt += 64) {
    __syncthreads();
    #pragma unroll
    for (int j = 0; j < 2; ++j) {
      const int c = j * 256 + tid;
      const int r = c >> 3;
      const int ce = ((c & 7) ^ (r & 7)) * 8;
      __builtin_amdgcn_global_load_lds(
          (const __attribute__((address_space(1))) void*)(A + (size_t)(mt * 64 + r) * lda + kt + ce),
          (__attribute__((address_space(3))) void*)((char*)As + c * 16), 16, 0, 0);
      __builtin_amdgcn_global_load_lds(
          (const __attribute__((address_space(1))) void*)(W + (size_t)(nt * 64 + r) * ldb + kt + ce),
          (__attribute__((address_space(3))) void*)((char*)Bs + c * 16), 16, 0, 0);
    }
    asm volatile("s_waitcnt vmcnt(0)" ::: "memory");
    __syncthreads();
    #pragma unroll
    for (int ks = 0; ks < 2; ++ks) {
      short8 a[2], bfr[2];
      #pragma unroll
      for (int m = 0; m < 2; ++m) {
        const int row = wr * 32 + m * 16 + lr;
        a[m] = *(const short8*)((char*)As + row * 128 + (((ks * 4 + lk) ^ (row & 7)) * 16));
      }
      #pragma unroll
      for (int n = 0; n < 2; ++n) {
        const int row = wc * 32 + n * 16 + lr;
        bfr[n] = *(const short8*)((char*)Bs + row * 128 + (((ks * 4 + lk) ^ (row & 7)) * 16));
      }
      #pragma unroll
      for (int m = 0; m < 2; ++m)
        #pragma unroll
        for (int n = 0; n < 2; ++n)
          acc[m][n] = __builtin_amdgcn_mfma_f32_16x16x32_bf16(a[m], bfr[n], acc[m][n], 0, 0, 0);
    }
  }
}

// Q projection: 256 blocks of 64x64
__global__ __launch_bounds__(256) void gemm_q64(
    const short* __restrict__ qx, const short* __restrict__ wqb,
    const float* __restrict__ b_q, short* __restrict__ Qo)
{
  __shared__ __align__(16) short As[64 * 64];
  __shared__ __align__(16) short Bs[64 * 64];
  const int bid = blockIdx.x;
  const int u = (bid & 7) * 32 + (bid >> 3);
  const int mt = u >> 4, nt = u & 15;

  f32x4 acc[2][2] = {};
  gemm64_core(qx, wqb, mt, nt, D_, D_, D_, acc, As, Bs);

  const int l = threadIdx.x & 63, w = threadIdx.x >> 6;
  const int wr = w >> 1, wc = w & 1;
  const int lr = l & 15, lk = l >> 4;
  #pragma unroll
  for (int n = 0; n < 2; ++n) {
    const int col = nt * 64 + wc * 32 + n * 16 + lr;
    const float bv = b_q[col];
    #pragma unroll
    for (int m = 0; m < 2; ++m) {
      const int row0 = mt * 64 + wr * 32 + m * 16 + lk * 4;
      #pragma unroll
      for (int i = 0; i < 4; ++i)
        Qo[(size_t)(row0 + i) * D_ + col] = f2bf(acc[m][n][i] + bv);
    }
  }
}

// ---------------------------------------------------------------------------
// gemm_qt: q~[bp,h,:] = Q[bp, h*64..h*64+63] @ wk[h*64.., :]  (K=64)
// ---------------------------------------------------------------------------
__global__ __launch_bounds__(256) void gemm_qt(
    const short* __restrict__ Qo, const short* __restrict__ wkT,
    short* __restrict__ Qt)
{
  __shared__ __align__(16) short As[128 * 64];
  __shared__ __align__(16) short Bs[128 * 64];
  const int bid = blockIdx.x;
  const int hh = bid >> 6, mt = (bid >> 3) & 7, nt = bid & 7;
  const int tid = threadIdx.x;
  const int wid = tid >> 6, l = tid & 63;
  const int wr = wid >> 1, wc = wid & 1;
  const int lr = l & 15, lk = l >> 4;
  const int sr = l >> 3, scol = (l & 7) * 8;

  #pragma unroll
  for (int j = 0; j < 4; ++j) {
    const int r = (wid * 4 + j) * 8 + sr;
    __builtin_amdgcn_global_load_lds(
        (const __attribute__((address_space(1))) void*)(Qo + (size_t)(mt * 128 + r) * D_ + hh * 64 + scol),
        (__attribute__((address_space(3))) void*)(As + (wid * 4 + j) * 512), 16, 0, 0);
    __builtin_amdgcn_global_load_lds(
        (const __attribute__((address_space(1))) void*)(wkT + (size_t)(nt * 128 + r) * D_ + hh * 64 + scol),
        (__attribute__((address_space(3))) void*)(Bs + (wid * 4 + j) * 512), 16, 0, 0);
  }
  asm volatile("s_waitcnt vmcnt(0)" ::: "memory");
  __syncthreads();

  f32x4 acc[4][4] = {};
  #pragma unroll
  for (int ks = 0; ks < 2; ++ks) {
    short8 a[4], bfr[4];
    #pragma unroll
    for (int m = 0; m < 4; ++m)
      a[m] = *(const short8*)(As + (wr * 64 + m * 16 + lr) * 64 + ks * 32 + lk * 8);
    #pragma unroll
    for (int n = 0; n < 4; ++n)
      bfr[n] = *(const short8*)(Bs + (wc * 64 + n * 16 + lr) * 64 + ks * 32 + lk * 8);
    #pragma unroll
    for (int m = 0; m < 4; ++m)
      #pragma unroll
      for (int n = 0; n < 4; ++n)
        acc[m][n] = __builtin_amdgcn_mfma_f32_16x16x32_bf16(a[m], bfr[n], acc[m][n], 0, 0, 0);
  }

  #pragma unroll
  for (int n = 0; n < 4; ++n) {
    const int col = nt * 128 + wc * 64 + n * 16 + lr;
    #pragma unroll
    for (int m = 0; m < 4; ++m) {
      const int row0 = mt * 128 + wr * 64 + m * 16 + lk * 4;
      #pragma unroll
      for (int i = 0; i < 4; ++i)
        Qt[((size_t)(row0 + i) * 16 + hh) * D_ + col] = f2bf(acc[m][n][i]);
    }
  }
}

// ---------------------------------------------------------------------------
// attn8: 1024 blocks x 1024 threads (16 waves). Per-thread state halved vs
// attn2 (xacc[16]: one d per thread; af[2]: wave owns 64 k's; softmax only
// on wave 0) targeting VGPR <= 64 so TWO 16-wave blocks co-reside per CU
// (32 waves/CU, double attn2's 16). LDS = Xs 32K + red 16K + small ~50.5KB.
// No forced min-occupancy (R6 spill lesson).
// ---------------------------------------------------------------------------
__global__ __launch_bounds__(1024) void attn8_kernel(
    const short* __restrict__ Qt, const float* __restrict__ X,
    const int* __restrict__ pos, const float* __restrict__ mask,
    short* __restrict__ Xbar)
{
  __shared__ __align__(16) short Xs[16 * 1024];   // 32KB, swizzled rows (2048B)
  __shared__ float attnT[16][16];                 // [t][h]
  __shared__ float rband[16];
  __shared__ float denL[16];
  __shared__ __align__(16) float red[16][256];    // 16KB reduce tree

  const int bp = blockIdx.x;
  const int b = bp >> 8;
  const int tid = threadIdx.x;
  const int w = tid >> 6, l = tid & 63;
  const int t_l = l & 15;
  const int lk = l >> 4;
  const int hgrp = lk * 4;

  // A-frags: wave w covers k-range w*64 .. w*64+63 (2 MFMA K-steps)
  short8 af0, af1;
  {
    const short* qb = Qt + ((size_t)bp * 16 + t_l) * D_;
    af0 = *(const short8*)(qb + w * 64 + lk * 8);
    af1 = *(const short8*)(qb + w * 64 + 32 + lk * 8);
  }

  const bool is64 = (pos[1] == 0);
  const int start = is64 ? pos[4 * bp]     : pos[2 * bp];
  const int end   = is64 ? pos[4 * bp + 2] : pos[2 * bp + 1];
  const bool valid = (start < S_) && (end <= S_) && (start < end);
  const int lo = valid ? (start < 0 ? 0 : start) : 0;
  const int hi = valid ? end : 0;

  float xacc[16];              // thread owns d = tid (one column)
  #pragma unroll
  for (int h = 0; h < 16; ++h) xacc[h] = 0.f;
  float m_run[4] = {-3.0e38f, -3.0e38f, -3.0e38f, -3.0e38f};
  float den[4] = {0.f, 0.f, 0.f, 0.f};   // meaningful only on wave 0

  for (int c0 = lo; c0 < hi; c0 += 16) {
    __syncthreads();
    // stage: 4 passes, 4 rows each (256 threads/row), float4 -> bf16x4
    #pragma unroll
    for (int j = 0; j < 4; ++j) {
      const int row = j * 4 + (tid >> 8);
      int rg = c0 + row; rg = rg < S_ ? rg : S_ - 1;
      const int c4 = (tid & 255) * 4;    // float index within row
      const float4 xv = *(const float4*)(X + ((size_t)b * S_ + rg) * D_ + c4);
      short4v o;
      o[0] = f2bf(xv.x); o[1] = f2bf(xv.y); o[2] = f2bf(xv.z); o[3] = f2bf(xv.w);
      *(short4v*)((char*)Xs + row * 2048 + ((c4 * 2) ^ ((row & 7) << 4))) = o;
    }
    __syncthreads();

    // scores: all 16 waves, wave w covers k = w*64 .. w*64+63
    f32x4 c = {};
    const int rsw = (t_l & 7) << 4;
    {
      const int kb0 = (w * 64 + lk * 8) * 2;
      const short8 x80 = *(const short8*)((char*)Xs + t_l * 2048 + (kb0 ^ rsw));
      c = __builtin_amdgcn_mfma_f32_16x16x32_bf16(af0, x80, c, 0, 0, 0);
      const int kb1 = (w * 64 + 32 + lk * 8) * 2;
      const short8 x81 = *(const short8*)((char*)Xs + t_l * 2048 + (kb1 ^ rsw));
      c = __builtin_amdgcn_mfma_f32_16x16x32_bf16(af1, x81, c, 0, 0, 0);
    }
    *(f32x4*)&red[w][l * 4] = c;
    __syncthreads();

    if (w == 0) {
      f32x4 s = *(const f32x4*)&red[0][l * 4];
      #pragma unroll
      for (int ww = 1; ww < 16; ++ww)
        s = s + *(const f32x4*)&red[ww][l * 4];

      const int tg = c0 + t_l;
      const bool ok = (tg < hi) && (mask[(size_t)b * S_ + tg] != 0.f);
      #pragma unroll
      for (int i = 0; i < 4; ++i) {
        const float sc = ok ? s[i] * 0.125f : -3.0e38f;
        float cm = sc;
        cm = fmaxf(cm, __shfl_xor(cm, 1, 64));
        cm = fmaxf(cm, __shfl_xor(cm, 2, 64));
        cm = fmaxf(cm, __shfl_xor(cm, 4, 64));
        cm = fmaxf(cm, __shfl_xor(cm, 8, 64));
        const float nm = fmaxf(m_run[i], cm);
        const float r = __expf(m_run[i] - nm);
        const float wv_ = ok ? __expf(sc - nm) : 0.f;
        float ws = wv_;
        ws += __shfl_xor(ws, 1, 64);
        ws += __shfl_xor(ws, 2, 64);
        ws += __shfl_xor(ws, 4, 64);
        ws += __shfl_xor(ws, 8, 64);
        den[i] = den[i] * r + ws;
        attnT[t_l][hgrp + i] = wv_;
        if (t_l == 0) rband[hgrp + i] = r;
        m_run[i] = nm;
      }
    }
    __syncthreads();

    // xbar: thread owns d = tid for all 16 h
    #pragma unroll
    for (int h = 0; h < 16; ++h) xacc[h] *= rband[h];
    #pragma unroll
    for (int t = 0; t < 16; ++t) {
      const f32x4 a0 = *(const f32x4*)&attnT[t][0];
      const f32x4 a1 = *(const f32x4*)&attnT[t][4];
      const f32x4 a2 = *(const f32x4*)&attnT[t][8];
      const f32x4 a3 = *(const f32x4*)&attnT[t][12];
      const short xvs = *(const short*)((char*)Xs + t * 2048 + ((tid * 2) ^ ((t & 7) << 4)));
      const float x0 = b2f(xvs);
      #pragma unroll
      for (int i = 0; i < 4; ++i) {
        xacc[i]      += a0[i] * x0;
        xacc[i + 4]  += a1[i] * x0;
        xacc[i + 8]  += a2[i] * x0;
        xacc[i + 12] += a3[i] * x0;
      }
    }
  }

  if (w == 0 && t_l == 0) {
    #pragma unroll
    for (int i = 0; i < 4; ++i) denL[hgrp + i] = den[i];
  }
  __syncthreads();

  bool need = false;
  #pragma unroll
  for (int h = 0; h < 16; ++h) need = need || (denL[h] <= 0.f);
  float ms = 0.f;
  if (need) {
    // reference fallback: uniform over ALL S
    for (int t = 0; t < S_; ++t)
      ms += X[((size_t)b * S_ + t) * D_ + tid];
    ms *= (1.f / S_);
  }
  #pragma unroll
  for (int h = 0; h < 16; ++h) {
    const float dL = denL[h];
    const float v = (dL > 0.f) ? (xacc[h] / dL) : ms;
    Xbar[((size_t)bp * 16 + h) * D_ + tid] = f2bf(v);
  }
}

// ---------------------------------------------------------------------------
// gemm_v64: AO[:, h*64..] = xbar_h @ wv_h^T + b_v. 256 blocks (16h x 16mt).
// ---------------------------------------------------------------------------
__global__ __launch_bounds__(256) void gemm_v64(
    const short* __restrict__ Xbar, const short* __restrict__ wvb,
    const float* __restrict__ b_v, short* __restrict__ AO)
{
  __shared__ __align__(16) short As[64 * 64];
  __shared__ __align__(16) short Bs[64 * 64];
  const int bid = blockIdx.x;
  const int u = (bid & 7) * 32 + (bid >> 3);
  const int h = u >> 4, mt = u & 15;

  f32x4 acc[2][2] = {};
  gemm64_core(Xbar + (size_t)h * D_, wvb + (size_t)h * 64 * D_,
              mt, 0, D_, 16 * D_, D_, acc, As, Bs);

  const int l = threadIdx.x & 63, w = threadIdx.x >> 6;
  const int wr = w >> 1, wc = w & 1;
  const int lr = l & 15, lk = l >> 4;
  #pragma unroll
  for (int n = 0; n < 2; ++n) {
    const int gcol = h * 64 + wc * 32 + n * 16 + lr;
    const float bv = b_v[gcol];
    #pragma unroll
    for (int m = 0; m < 2; ++m) {
      const int row0 = mt * 64 + wr * 32 + m * 16 + lk * 4;
      #pragma unroll
      for (int i = 0; i < 4; ++i)
        AO[(size_t)(row0 + i) * D_ + gcol] = f2bf(acc[m][n][i] + bv);
    }
  }
}

// O projection + bias + residual, fp32 out. 256 blocks of 64x64.
__global__ __launch_bounds__(256) void gemm_o64(
    const short* __restrict__ AO, const short* __restrict__ wob,
    const float* __restrict__ b_o, const float* __restrict__ pe,
    float* __restrict__ out)
{
  __shared__ __align__(16) short As[64 * 64];
  __shared__ __align__(16) short Bs[64 * 64];
  const int bid = blockIdx.x;
  const int u = (bid & 7) * 32 + (bid >> 3);
  const int mt = u >> 4, nt = u & 15;

  f32x4 acc[2][2] = {};
  gemm64_core(AO, wob, mt, nt, D_, D_, D_, acc, As, Bs);

  const int l = threadIdx.x & 63, w = threadIdx.x >> 6;
  const int wr = w >> 1, wc = w & 1;
  const int lr = l & 15, lk = l >> 4;
  #pragma unroll
  for (int n = 0; n < 2; ++n) {
    const int col = nt * 64 + wc * 32 + n * 16 + lr;
    const float bv = b_o[col];
    #pragma unroll
    for (int m = 0; m < 2; ++m) {
      const int row0 = mt * 64 + wr * 32 + m * 16 + lk * 4;
      #pragma unroll
      for (int i = 0; i < 4; ++i) {
        const size_t idx = (size_t)(row0 + i) * D_ + col;
        out[idx] = acc[m][n][i] + bv + pe[idx];
      }
    }
  }
}

// ---------------------------------------------------------------------------
extern "C" void kernel_launch(void* const* d_in, const int* in_sizes, int n_in,
                              void* d_out, int out_size, void* d_ws, size_t ws_size,
                              hipStream_t stream)
{
  const float* pe    = (const float*)d_in[0];
  const float* xby   = (const float*)d_in[1];
  const int*   pos   = (const int*)d_in[2];
  const float* mask  = (const float*)d_in[3];
  const float* gamma = (const float*)d_in[4];
  const float* beta  = (const float*)d_in[5];
  const float* w_q   = (const float*)d_in[6];
  const float* b_q   = (const float*)d_in[7];
  const float* w_k   = (const float*)d_in[8];
  const float* b_k   = (const float*)d_in[9];  (void)b_k; // softmax-shift invariant
  const float* w_v   = (const float*)d_in[10];
  const float* b_v   = (const float*)d_in[11];
  const float* w_o   = (const float*)d_in[12];
  const float* b_o   = (const float*)d_in[13];

  char* ws = (char*)d_ws;
  short* Qt   = (short*)(ws);                // 32 MB: q~ [bp*16+h][1024] bf16
  short* Xbar = (short*)(ws + 33554432);     // 32 MB: xbar same layout
  short* wqb  = (short*)(ws + 67108864);     // 2 MB each
  short* wvb  = (short*)(ws + 69206016);
  short* wob  = (short*)(ws + 71303168);
  short* wkT  = (short*)(ws + 73400320);     // 2 MB: wk transposed bf16
  short* qx   = (short*)(ws + 75497472);     // 2 MB: LN(pe) bf16
  short* Qo   = (short*)(ws + 77594624);     // 2 MB: Q bf16
  short* AO   = (short*)(ws + 79691776);     // 2 MB: attention out bf16
  (void)in_sizes; (void)n_in; (void)out_size; (void)ws_size;

  prep2_kernel<<<2624, 256, 0, stream>>>(pe, gamma, beta, w_q, w_k, w_v, w_o,
                                         wqb, wvb, wob, wkT, qx);
  gemm_q64<<<256, 256, 0, stream>>>(qx, wqb, b_q, Qo);
  gemm_qt<<<1024, 256, 0, stream>>>(Qo, wkT, Qt);
  attn8_kernel<<<1024, 1024, 0, stream>>>(Qt, xby, pos, mask, Xbar);
  gemm_v64<<<256, 256, 0, stream>>>(Xbar, wvb, b_v, AO);
  gemm_o64<<<256, 256, 0, stream>>>(AO, wob, b_o, pe, (float*)d_out);
}

// Round 18
// 101.158 us; speedup vs baseline: 1.3989x; 1.3989x over previous
//
#include <hip/hip_runtime.h>
#include <hip/hip_bf16.h>
#include <stdint.h>

#define B_ 4
#define P_ 256
#define S_ 4096
#define D_ 1024
#define H_ 16
#define HD_ 64

typedef __attribute__((ext_vector_type(8))) short short8;
typedef __attribute__((ext_vector_type(4))) short short4v;
typedef __attribute__((ext_vector_type(2))) short short2v;
typedef __attribute__((ext_vector_type(4))) float f32x4;

__device__ __forceinline__ float b2f(short s) {
  return __uint_as_float(((unsigned)(unsigned short)s) << 16);
}
__device__ __forceinline__ short f2bf(float f) {
  unsigned u = __float_as_uint(f);
  unsigned r = (u + 0x7fffu + ((u >> 16) & 1u)) >> 16;
  return (short)(unsigned short)r;
}

// ---------------------------------------------------------------------------
// prep2: wq,wv,wo -> bf16; wk -> bf16 TRANSPOSED (wkT); LN(pe) -> qx
// ---------------------------------------------------------------------------
__global__ __launch_bounds__(256) void prep2_kernel(
    const float* __restrict__ pe,
    const float* __restrict__ gamma, const float* __restrict__ beta,
    const float* __restrict__ wq, const float* __restrict__ wk,
    const float* __restrict__ wv, const float* __restrict__ wo,
    short* __restrict__ wqb, short* __restrict__ wvb, short* __restrict__ wob,
    short* __restrict__ wkT, short* __restrict__ qx)
{
  const int bid = blockIdx.x;
  const int tid = threadIdx.x;
  if (bid < 1536) {
    const int wi = bid >> 9;
    const size_t base = (size_t)(bid & 511) * 2048 + (size_t)tid * 8;
    const float* src; short* dst;
    if (wi == 0)      { src = wq; dst = wqb; }
    else if (wi == 1) { src = wv; dst = wvb; }
    else              { src = wo; dst = wob; }
    const float4 f0 = *(const float4*)(src + base);
    const float4 f1 = *(const float4*)(src + base + 4);
    short8 o;
    o[0] = f2bf(f0.x); o[1] = f2bf(f0.y); o[2] = f2bf(f0.z); o[3] = f2bf(f0.w);
    o[4] = f2bf(f1.x); o[5] = f2bf(f1.y); o[6] = f2bf(f1.z); o[7] = f2bf(f1.w);
    *(short8*)(dst + base) = o;
  } else if (bid < 1600) {
    __shared__ short Ts[128][132];
    const int t = bid - 1536;
    const int ti = t >> 3, tj = t & 7;
    #pragma unroll
    for (int j = 0; j < 16; ++j) {
      const int r = j * 8 + (tid >> 5);
      const int c4 = (tid & 31) * 4;
      const float4 v = *(const float4*)(wk + (size_t)(ti * 128 + r) * D_ + tj * 128 + c4);
      short4v o;
      o[0] = f2bf(v.x); o[1] = f2bf(v.y); o[2] = f2bf(v.z); o[3] = f2bf(v.w);
      *(short4v*)(&Ts[r][c4]) = o;
    }
    __syncthreads();
    #pragma unroll
    for (int j = 0; j < 16; ++j) {
      const int c = j * 8 + (tid >> 5);
      const int r4 = (tid & 31) * 4;
      short4v o;
      o[0] = Ts[r4 + 0][c]; o[1] = Ts[r4 + 1][c];
      o[2] = Ts[r4 + 2][c]; o[3] = Ts[r4 + 3][c];
      *(short4v*)(wkT + (size_t)(tj * 128 + c) * D_ + ti * 128 + r4) = o;
    }
  } else {
    const int row = bid - 1600;
    const int c = tid * 4;
    const float4 x = *(const float4*)(pe + (size_t)row * D_ + c);
    float s1 = x.x + x.y + x.z + x.w;
    float s2 = x.x * x.x + x.y * x.y + x.z * x.z + x.w * x.w;
    #pragma unroll
    for (int off = 32; off >= 1; off >>= 1) {
      s1 += __shfl_xor(s1, off, 64);
      s2 += __shfl_xor(s2, off, 64);
    }
    __shared__ float red[8];
    const int wid = tid >> 6, lane = tid & 63;
    if (lane == 0) { red[wid] = s1; red[4 + wid] = s2; }
    __syncthreads();
    s1 = red[0] + red[1] + red[2] + red[3];
    s2 = red[4] + red[5] + red[6] + red[7];
    const float mu = s1 * (1.0f / D_);
    const float var = s2 * (1.0f / D_) - mu * mu;
    const float rs = rsqrtf(var + 1e-5f);
    const float4 g = *(const float4*)(gamma + c);
    const float4 bt = *(const float4*)(beta + c);
    short4v o;
    o[0] = f2bf((x.x - mu) * rs * g.x + bt.x);
    o[1] = f2bf((x.y - mu) * rs * g.y + bt.y);
    o[2] = f2bf((x.z - mu) * rs * g.z + bt.z);
    o[3] = f2bf((x.w - mu) * rs * g.w + bt.w);
    *(short4v*)(qx + (size_t)row * D_ + c) = o;
  }
}

// ---------------------------------------------------------------------------
// 64x64-tile GEMM core (R10 single-buffer, measured-best)
// ---------------------------------------------------------------------------
__device__ __forceinline__ void gemm64_core(
    const short* __restrict__ A, const short* __restrict__ W,
    int mt, int nt, int Kd, int lda, int ldb,
    f32x4 acc[2][2], short* As, short* Bs)
{
  const int tid = threadIdx.x;
  const int w = tid >> 6, l = tid & 63;
  const int wr = w >> 1, wc = w & 1;
  const int lr = l & 15, lk = l >> 4;
  (void)l; (void)w;

  for (int kt = 0; kt < Kd; kt += 64) {
    __syncthreads();
    #pragma unroll
    for (int j = 0; j < 2; ++j) {
      const int c = j * 256 + tid;
      const int r = c >> 3;
      const int ce = ((c & 7) ^ (r & 7)) * 8;
      __builtin_amdgcn_global_load_lds(
          (const __attribute__((address_space(1))) void*)(A + (size_t)(mt * 64 + r) * lda + kt + ce),
          (__attribute__((address_space(3))) void*)((char*)As + c * 16), 16, 0, 0);
      __builtin_amdgcn_global_load_lds(
          (const __attribute__((address_space(1))) void*)(W + (size_t)(nt * 64 + r) * ldb + kt + ce),
          (__attribute__((address_space(3))) void*)((char*)Bs + c * 16), 16, 0, 0);
    }
    asm volatile("s_waitcnt vmcnt(0)" ::: "memory");
    __syncthreads();
    #pragma unroll
    for (int ks = 0; ks < 2; ++ks) {
      short8 a[2], bfr[2];
      #pragma unroll
      for (int m = 0; m < 2; ++m) {
        const int row = wr * 32 + m * 16 + lr;
        a[m] = *(const short8*)((char*)As + row * 128 + (((ks * 4 + lk) ^ (row & 7)) * 16));
      }
      #pragma unroll
      for (int n = 0; n < 2; ++n) {
        const int row = wc * 32 + n * 16 + lr;
        bfr[n] = *(const short8*)((char*)Bs + row * 128 + (((ks * 4 + lk) ^ (row & 7)) * 16));
      }
      #pragma unroll
      for (int m = 0; m < 2; ++m)
        #pragma unroll
        for (int n = 0; n < 2; ++n)
          acc[m][n] = __builtin_amdgcn_mfma_f32_16x16x32_bf16(a[m], bfr[n], acc[m][n], 0, 0, 0);
    }
  }
}

// Q projection: 256 blocks of 64x64
__global__ __launch_bounds__(256) void gemm_q64(
    const short* __restrict__ qx, const short* __restrict__ wqb,
    const float* __restrict__ b_q, short* __restrict__ Qo)
{
  __shared__ __align__(16) short As[64 * 64];
  __shared__ __align__(16) short Bs[64 * 64];
  const int bid = blockIdx.x;
  const int u = (bid & 7) * 32 + (bid >> 3);
  const int mt = u >> 4, nt = u & 15;

  f32x4 acc[2][2] = {};
  gemm64_core(qx, wqb, mt, nt, D_, D_, D_, acc, As, Bs);

  const int l = threadIdx.x & 63, w = threadIdx.x >> 6;
  const int wr = w >> 1, wc = w & 1;
  const int lr = l & 15, lk = l >> 4;
  #pragma unroll
  for (int n = 0; n < 2; ++n) {
    const int col = nt * 64 + wc * 32 + n * 16 + lr;
    const float bv = b_q[col];
    #pragma unroll
    for (int m = 0; m < 2; ++m) {
      const int row0 = mt * 64 + wr * 32 + m * 16 + lk * 4;
      #pragma unroll
      for (int i = 0; i < 4; ++i)
        Qo[(size_t)(row0 + i) * D_ + col] = f2bf(acc[m][n][i] + bv);
    }
  }
}

// ---------------------------------------------------------------------------
// gemm_qt: q~[bp,h,:] = Q[bp, h*64..h*64+63] @ wk[h*64.., :]  (K=64)
// ---------------------------------------------------------------------------
__global__ __launch_bounds__(256) void gemm_qt(
    const short* __restrict__ Qo, const short* __restrict__ wkT,
    short* __restrict__ Qt)
{
  __shared__ __align__(16) short As[128 * 64];
  __shared__ __align__(16) short Bs[128 * 64];
  const int bid = blockIdx.x;
  const int hh = bid >> 6, mt = (bid >> 3) & 7, nt = bid & 7;
  const int tid = threadIdx.x;
  const int wid = tid >> 6, l = tid & 63;
  const int wr = wid >> 1, wc = wid & 1;
  const int lr = l & 15, lk = l >> 4;
  const int sr = l >> 3, scol = (l & 7) * 8;

  #pragma unroll
  for (int j = 0; j < 4; ++j) {
    const int r = (wid * 4 + j) * 8 + sr;
    __builtin_amdgcn_global_load_lds(
        (const __attribute__((address_space(1))) void*)(Qo + (size_t)(mt * 128 + r) * D_ + hh * 64 + scol),
        (__attribute__((address_space(3))) void*)(As + (wid * 4 + j) * 512), 16, 0, 0);
    __builtin_amdgcn_global_load_lds(
        (const __attribute__((address_space(1))) void*)(wkT + (size_t)(nt * 128 + r) * D_ + hh * 64 + scol),
        (__attribute__((address_space(3))) void*)(Bs + (wid * 4 + j) * 512), 16, 0, 0);
  }
  asm volatile("s_waitcnt vmcnt(0)" ::: "memory");
  __syncthreads();

  f32x4 acc[4][4] = {};
  #pragma unroll
  for (int ks = 0; ks < 2; ++ks) {
    short8 a[4], bfr[4];
    #pragma unroll
    for (int m = 0; m < 4; ++m)
      a[m] = *(const short8*)(As + (wr * 64 + m * 16 + lr) * 64 + ks * 32 + lk * 8);
    #pragma unroll
    for (int n = 0; n < 4; ++n)
      bfr[n] = *(const short8*)(Bs + (wc * 64 + n * 16 + lr) * 64 + ks * 32 + lk * 8);
    #pragma unroll
    for (int m = 0; m < 4; ++m)
      #pragma unroll
      for (int n = 0; n < 4; ++n)
        acc[m][n] = __builtin_amdgcn_mfma_f32_16x16x32_bf16(a[m], bfr[n], acc[m][n], 0, 0, 0);
  }

  #pragma unroll
  for (int n = 0; n < 4; ++n) {
    const int col = nt * 128 + wc * 64 + n * 16 + lr;
    #pragma unroll
    for (int m = 0; m < 4; ++m) {
      const int row0 = mt * 128 + wr * 64 + m * 16 + lk * 4;
      #pragma unroll
      for (int i = 0; i < 4; ++i)
        Qt[((size_t)(row0 + i) * 16 + hh) * D_ + col] = f2bf(acc[m][n][i]);
    }
  }
}

// ---------------------------------------------------------------------------
// attn2 v3 (R10 verbatim, measured 52us): per (b,p) block, 512 threads.
// xacc[16][2], af[4]; score MFMA split over 8 waves, 8KB LDS reduce tree.
// float2 x16 staging (measured better than float4 x8 in R16).
// ---------------------------------------------------------------------------
__global__ __launch_bounds__(512) void attn2_kernel(
    const short* __restrict__ Qt, const float* __restrict__ X,
    const int* __restrict__ pos, const float* __restrict__ mask,
    short* __restrict__ Xbar)
{
  __shared__ __align__(16) short Xs[16 * 1024];   // 32KB, swizzled rows of 2048B
  __shared__ float attnT[16][16];                 // [t][h]
  __shared__ float rband[16];
  __shared__ float denL[16];
  __shared__ __align__(16) float red[8][256];     // 8KB reduce tree

  const int bp = blockIdx.x;
  const int b = bp >> 8;
  const int tid = threadIdx.x;
  const int w = tid >> 6, l = tid & 63;
  const int t_l = l & 15;
  const int lk = l >> 4;
  const int hgrp = lk * 4;

  short8 af[4];
  {
    const short* qb = Qt + ((size_t)bp * 16 + t_l) * D_;
    #pragma unroll
    for (int ks = 0; ks < 4; ++ks)
      af[ks] = *(const short8*)(qb + (w * 4 + ks) * 32 + lk * 8);
  }

  const bool is64 = (pos[1] == 0);
  const int start = is64 ? pos[4 * bp]     : pos[2 * bp];
  const int end   = is64 ? pos[4 * bp + 2] : pos[2 * bp + 1];
  const bool valid = (start < S_) && (end <= S_) && (start < end);
  const int lo = valid ? (start < 0 ? 0 : start) : 0;
  const int hi = valid ? end : 0;

  float xacc[16][2];
  #pragma unroll
  for (int h = 0; h < 16; ++h) { xacc[h][0] = 0.f; xacc[h][1] = 0.f; }
  float m_run[4] = {-3.0e38f, -3.0e38f, -3.0e38f, -3.0e38f};
  float den[4] = {0.f, 0.f, 0.f, 0.f};

  for (int c0 = lo; c0 < hi; c0 += 16) {
    __syncthreads();
    #pragma unroll
    for (int j = 0; j < 16; ++j) {
      int rg = c0 + j; rg = rg < S_ ? rg : S_ - 1;
      const float2 xv = *(const float2*)(X + ((size_t)b * S_ + rg) * D_ + tid * 2);
      short2v o;
      o[0] = f2bf(xv.x); o[1] = f2bf(xv.y);
      *(short2v*)((char*)Xs + j * 2048 + ((tid * 4) ^ ((j & 7) << 4))) = o;
    }
    __syncthreads();

    f32x4 c = {};
    const int rsw = (t_l & 7) << 4;
    #pragma unroll
    for (int ks = 0; ks < 4; ++ks) {
      const int kb = ((w * 4 + ks) * 32 + lk * 8) * 2;
      const short8 x8 = *(const short8*)((char*)Xs + t_l * 2048 + (kb ^ rsw));
      c = __builtin_amdgcn_mfma_f32_16x16x32_bf16(af[ks], x8, c, 0, 0, 0);
    }
    *(f32x4*)&red[w][l * 4] = c;
    __syncthreads();
    f32x4 s = *(const f32x4*)&red[0][l * 4];
    #pragma unroll
    for (int ww = 1; ww < 8; ++ww)
      s = s + *(const f32x4*)&red[ww][l * 4];

    const int tg = c0 + t_l;
    const bool ok = (tg < hi) && (mask[(size_t)b * S_ + tg] != 0.f);
    float wgt[4], rr[4];
    #pragma unroll
    for (int i = 0; i < 4; ++i) {
      const float sc = ok ? s[i] * 0.125f : -3.0e38f;
      float cm = sc;
      cm = fmaxf(cm, __shfl_xor(cm, 1, 64));
      cm = fmaxf(cm, __shfl_xor(cm, 2, 64));
      cm = fmaxf(cm, __shfl_xor(cm, 4, 64));
      cm = fmaxf(cm, __shfl_xor(cm, 8, 64));
      const float nm = fmaxf(m_run[i], cm);
      const float r = __expf(m_run[i] - nm);
      const float wv_ = ok ? __expf(sc - nm) : 0.f;
      float ws = wv_;
      ws += __shfl_xor(ws, 1, 64);
      ws += __shfl_xor(ws, 2, 64);
      ws += __shfl_xor(ws, 4, 64);
      ws += __shfl_xor(ws, 8, 64);
      den[i] = den[i] * r + ws;
      m_run[i] = nm;
      wgt[i] = wv_; rr[i] = r;
    }
    if (w == 0) {
      #pragma unroll
      for (int i = 0; i < 4; ++i) attnT[t_l][hgrp + i] = wgt[i];
      if (t_l == 0) {
        #pragma unroll
        for (int i = 0; i < 4; ++i) rband[hgrp + i] = rr[i];
      }
    }
    __syncthreads();

    #pragma unroll
    for (int h = 0; h < 16; ++h) {
      const float rb = rband[h];
      xacc[h][0] *= rb; xacc[h][1] *= rb;
    }
    #pragma unroll
    for (int t = 0; t < 16; ++t) {
      const f32x4 a0 = *(const f32x4*)&attnT[t][0];
      const f32x4 a1 = *(const f32x4*)&attnT[t][4];
      const f32x4 a2 = *(const f32x4*)&attnT[t][8];
      const f32x4 a3 = *(const f32x4*)&attnT[t][12];
      const short2v xv = *(const short2v*)((char*)Xs + t * 2048 + ((tid * 4) ^ ((t & 7) << 4)));
      const float x0 = b2f(xv[0]), x1 = b2f(xv[1]);
      #pragma unroll
      for (int i = 0; i < 4; ++i) {
        xacc[i][0]      += a0[i] * x0; xacc[i][1]      += a0[i] * x1;
        xacc[i + 4][0]  += a1[i] * x0; xacc[i + 4][1]  += a1[i] * x1;
        xacc[i + 8][0]  += a2[i] * x0; xacc[i + 8][1]  += a2[i] * x1;
        xacc[i + 12][0] += a3[i] * x0; xacc[i + 12][1] += a3[i] * x1;
      }
    }
  }

  if (w == 0 && t_l == 0) {
    #pragma unroll
    for (int i = 0; i < 4; ++i) denL[hgrp + i] = den[i];
  }
  __syncthreads();

  bool need = false;
  #pragma unroll
  for (int h = 0; h < 16; ++h) need = need || (denL[h] <= 0.f);
  float ms[2] = {0.f, 0.f};
  if (need) {
    for (int t = 0; t < S_; ++t) {
      const float2 xv = *(const float2*)(X + ((size_t)b * S_ + t) * D_ + tid * 2);
      ms[0] += xv.x; ms[1] += xv.y;
    }
    ms[0] *= (1.f / S_); ms[1] *= (1.f / S_);
  }
  #pragma unroll
  for (int h = 0; h < 16; ++h) {
    const float dL = denL[h];
    short2v o;
    if (dL > 0.f) {
      const float inv = 1.f / dL;
      o[0] = f2bf(xacc[h][0] * inv); o[1] = f2bf(xacc[h][1] * inv);
    } else {
      o[0] = f2bf(ms[0]); o[1] = f2bf(ms[1]);
    }
    *(short2v*)(Xbar + ((size_t)bp * 16 + h) * D_ + tid * 2) = o;
  }
}

// ---------------------------------------------------------------------------
// gemm_v64: AO[:, h*64..] = xbar_h @ wv_h^T + b_v. 256 blocks (16h x 16mt).
// ---------------------------------------------------------------------------
__global__ __launch_bounds__(256) void gemm_v64(
    const short* __restrict__ Xbar, const short* __restrict__ wvb,
    const float* __restrict__ b_v, short* __restrict__ AO)
{
  __shared__ __align__(16) short As[64 * 64];
  __shared__ __align__(16) short Bs[64 * 64];
  const int bid = blockIdx.x;
  const int u = (bid & 7) * 32 + (bid >> 3);
  const int h = u >> 4, mt = u & 15;

  f32x4 acc[2][2] = {};
  gemm64_core(Xbar + (size_t)h * D_, wvb + (size_t)h * 64 * D_,
              mt, 0, D_, 16 * D_, D_, acc, As, Bs);

  const int l = threadIdx.x & 63, w = threadIdx.x >> 6;
  const int wr = w >> 1, wc = w & 1;
  const int lr = l & 15, lk = l >> 4;
  #pragma unroll
  for (int n = 0; n < 2; ++n) {
    const int gcol = h * 64 + wc * 32 + n * 16 + lr;
    const float bv = b_v[gcol];
    #pragma unroll
    for (int m = 0; m < 2; ++m) {
      const int row0 = mt * 64 + wr * 32 + m * 16 + lk * 4;
      #pragma unroll
      for (int i = 0; i < 4; ++i)
        AO[(size_t)(row0 + i) * D_ + gcol] = f2bf(acc[m][n][i] + bv);
    }
  }
}

// O projection + bias + residual, fp32 out. 256 blocks of 64x64.
__global__ __launch_bounds__(256) void gemm_o64(
    const short* __restrict__ AO, const short* __restrict__ wob,
    const float* __restrict__ b_o, const float* __restrict__ pe,
    float* __restrict__ out)
{
  __shared__ __align__(16) short As[64 * 64];
  __shared__ __align__(16) short Bs[64 * 64];
  const int bid = blockIdx.x;
  const int u = (bid & 7) * 32 + (bid >> 3);
  const int mt = u >> 4, nt = u & 15;

  f32x4 acc[2][2] = {};
  gemm64_core(AO, wob, mt, nt, D_, D_, D_, acc, As, Bs);

  const int l = threadIdx.x & 63, w = threadIdx.x >> 6;
  const int wr = w >> 1, wc = w & 1;
  const int lr = l & 15, lk = l >> 4;
  #pragma unroll
  for (int n = 0; n < 2; ++n) {
    const int col = nt * 64 + wc * 32 + n * 16 + lr;
    const float bv = b_o[col];
    #pragma unroll
    for (int m = 0; m < 2; ++m) {
      const int row0 = mt * 64 + wr * 32 + m * 16 + lk * 4;
      #pragma unroll
      for (int i = 0; i < 4; ++i) {
        const size_t idx = (size_t)(row0 + i) * D_ + col;
        out[idx] = acc[m][n][i] + bv + pe[idx];
      }
    }
  }
}

// ---------------------------------------------------------------------------
extern "C" void kernel_launch(void* const* d_in, const int* in_sizes, int n_in,
                              void* d_out, int out_size, void* d_ws, size_t ws_size,
                              hipStream_t stream)
{
  const float* pe    = (const float*)d_in[0];
  const float* xby   = (const float*)d_in[1];
  const int*   pos   = (const int*)d_in[2];
  const float* mask  = (const float*)d_in[3];
  const float* gamma = (const float*)d_in[4];
  const float* beta  = (const float*)d_in[5];
  const float* w_q   = (const float*)d_in[6];
  const float* b_q   = (const float*)d_in[7];
  const float* w_k   = (const float*)d_in[8];
  const float* b_k   = (const float*)d_in[9];  (void)b_k; // softmax-shift invariant
  const float* w_v   = (const float*)d_in[10];
  const float* b_v   = (const float*)d_in[11];
  const float* w_o   = (const float*)d_in[12];
  const float* b_o   = (const float*)d_in[13];

  char* ws = (char*)d_ws;
  short* Qt   = (short*)(ws);                // 32 MB: q~ [bp*16+h][1024] bf16
  short* Xbar = (short*)(ws + 33554432);     // 32 MB: xbar same layout
  short* wqb  = (short*)(ws + 67108864);     // 2 MB each
  short* wvb  = (short*)(ws + 69206016);
  short* wob  = (short*)(ws + 71303168);
  short* wkT  = (short*)(ws + 73400320);     // 2 MB: wk transposed bf16
  short* qx   = (short*)(ws + 75497472);     // 2 MB: LN(pe) bf16
  short* Qo   = (short*)(ws + 77594624);     // 2 MB: Q bf16
  short* AO   = (short*)(ws + 79691776);     // 2 MB: attention out bf16
  (void)in_sizes; (void)n_in; (void)out_size; (void)ws_size;

  prep2_kernel<<<2624, 256, 0, stream>>>(pe, gamma, beta, w_q, w_k, w_v, w_o,
                                         wqb, wvb, wob, wkT, qx);
  gemm_q64<<<256, 256, 0, stream>>>(qx, wqb, b_q, Qo);
  gemm_qt<<<1024, 256, 0, stream>>>(Qo, wkT, Qt);
  attn2_kernel<<<1024, 512, 0, stream>>>(Qt, xby, pos, mask, Xbar);
  gemm_v64<<<256, 256, 0, stream>>>(Xbar, wvb, b_v, AO);
  gemm_o64<<<256, 256, 0, stream>>>(AO, wob, b_o, pe, (float*)d_out);
}

// Round 19
// 96.277 us; speedup vs baseline: 1.4698x; 1.0507x over previous
//
#include <hip/hip_runtime.h>
#include <hip/hip_bf16.h>
#include <stdint.h>

#define B_ 4
#define P_ 256
#define S_ 4096
#define D_ 1024
#define H_ 16
#define HD_ 64

typedef __attribute__((ext_vector_type(8))) short short8;
typedef __attribute__((ext_vector_type(4))) short short4v;
typedef __attribute__((ext_vector_type(2))) short short2v;
typedef __attribute__((ext_vector_type(4))) float f32x4;

__device__ __forceinline__ float b2f(short s) {
  return __uint_as_float(((unsigned)(unsigned short)s) << 16);
}
__device__ __forceinline__ short f2bf(float f) {
  unsigned u = __float_as_uint(f);
  unsigned r = (u + 0x7fffu + ((u >> 16) & 1u)) >> 16;
  return (short)(unsigned short)r;
}

// ---------------------------------------------------------------------------
// prep2: wq,wv,wo -> bf16; wk -> bf16 TRANSPOSED (wkT); LN(pe) -> qx
// ---------------------------------------------------------------------------
__global__ __launch_bounds__(256) void prep2_kernel(
    const float* __restrict__ pe,
    const float* __restrict__ gamma, const float* __restrict__ beta,
    const float* __restrict__ wq, const float* __restrict__ wk,
    const float* __restrict__ wv, const float* __restrict__ wo,
    short* __restrict__ wqb, short* __restrict__ wvb, short* __restrict__ wob,
    short* __restrict__ wkT, short* __restrict__ qx)
{
  const int bid = blockIdx.x;
  const int tid = threadIdx.x;
  if (bid < 1536) {
    const int wi = bid >> 9;
    const size_t base = (size_t)(bid & 511) * 2048 + (size_t)tid * 8;
    const float* src; short* dst;
    if (wi == 0)      { src = wq; dst = wqb; }
    else if (wi == 1) { src = wv; dst = wvb; }
    else              { src = wo; dst = wob; }
    const float4 f0 = *(const float4*)(src + base);
    const float4 f1 = *(const float4*)(src + base + 4);
    short8 o;
    o[0] = f2bf(f0.x); o[1] = f2bf(f0.y); o[2] = f2bf(f0.z); o[3] = f2bf(f0.w);
    o[4] = f2bf(f1.x); o[5] = f2bf(f1.y); o[6] = f2bf(f1.z); o[7] = f2bf(f1.w);
    *(short8*)(dst + base) = o;
  } else if (bid < 1600) {
    __shared__ short Ts[128][132];
    const int t = bid - 1536;
    const int ti = t >> 3, tj = t & 7;
    #pragma unroll
    for (int j = 0; j < 16; ++j) {
      const int r = j * 8 + (tid >> 5);
      const int c4 = (tid & 31) * 4;
      const float4 v = *(const float4*)(wk + (size_t)(ti * 128 + r) * D_ + tj * 128 + c4);
      short4v o;
      o[0] = f2bf(v.x); o[1] = f2bf(v.y); o[2] = f2bf(v.z); o[3] = f2bf(v.w);
      *(short4v*)(&Ts[r][c4]) = o;
    }
    __syncthreads();
    #pragma unroll
    for (int j = 0; j < 16; ++j) {
      const int c = j * 8 + (tid >> 5);
      const int r4 = (tid & 31) * 4;
      short4v o;
      o[0] = Ts[r4 + 0][c]; o[1] = Ts[r4 + 1][c];
      o[2] = Ts[r4 + 2][c]; o[3] = Ts[r4 + 3][c];
      *(short4v*)(wkT + (size_t)(tj * 128 + c) * D_ + ti * 128 + r4) = o;
    }
  } else {
    const int row = bid - 1600;
    const int c = tid * 4;
    const float4 x = *(const float4*)(pe + (size_t)row * D_ + c);
    float s1 = x.x + x.y + x.z + x.w;
    float s2 = x.x * x.x + x.y * x.y + x.z * x.z + x.w * x.w;
    #pragma unroll
    for (int off = 32; off >= 1; off >>= 1) {
      s1 += __shfl_xor(s1, off, 64);
      s2 += __shfl_xor(s2, off, 64);
    }
    __shared__ float red[8];
    const int wid = tid >> 6, lane = tid & 63;
    if (lane == 0) { red[wid] = s1; red[4 + wid] = s2; }
    __syncthreads();
    s1 = red[0] + red[1] + red[2] + red[3];
    s2 = red[4] + red[5] + red[6] + red[7];
    const float mu = s1 * (1.0f / D_);
    const float var = s2 * (1.0f / D_) - mu * mu;
    const float rs = rsqrtf(var + 1e-5f);
    const float4 g = *(const float4*)(gamma + c);
    const float4 bt = *(const float4*)(beta + c);
    short4v o;
    o[0] = f2bf((x.x - mu) * rs * g.x + bt.x);
    o[1] = f2bf((x.y - mu) * rs * g.y + bt.y);
    o[2] = f2bf((x.z - mu) * rs * g.z + bt.z);
    o[3] = f2bf((x.w - mu) * rs * g.w + bt.w);
    *(short4v*)(qx + (size_t)row * D_ + c) = o;
  }
}

// ---------------------------------------------------------------------------
// 64x64-tile GEMM core, BK=128 (8 K-tiles for K=1024 -> half the vmcnt(0)
// drains of the BK=64 version). 4 waves, 2x2 frags. Both-sides XOR swizzle
// at 16B granules: write chunk c -> linear granule (c&15) of row r with
// pre-swizzled source col ((c&15)^(r&15))*8; read granule (ks*4+lk)^(row&15).
// Lanes cover 16 distinct granules -> 2-way bank aliasing (free, m136).
// ---------------------------------------------------------------------------
__device__ __forceinline__ void gemm64_core(
    const short* __restrict__ A, const short* __restrict__ W,
    int mt, int nt, int Kd, int lda, int ldb,
    f32x4 acc[2][2], short* As, short* Bs)
{
  const int tid = threadIdx.x;
  const int w = tid >> 6, l = tid & 63;
  const int wr = w >> 1, wc = w & 1;
  const int lr = l & 15, lk = l >> 4;
  (void)l; (void)w;

  for (int kt = 0; kt < Kd; kt += 128) {
    __syncthreads();
    #pragma unroll
    for (int j = 0; j < 4; ++j) {
      const int c = j * 256 + tid;            // chunk 0..1023 (16B each)
      const int r = c >> 4;                   // tile row 0..63
      const int ce = ((c & 15) ^ (r & 15)) * 8;  // pre-swizzled source col
      __builtin_amdgcn_global_load_lds(
          (const __attribute__((address_space(1))) void*)(A + (size_t)(mt * 64 + r) * lda + kt + ce),
          (__attribute__((address_space(3))) void*)((char*)As + c * 16), 16, 0, 0);
      __builtin_amdgcn_global_load_lds(
          (const __attribute__((address_space(1))) void*)(W + (size_t)(nt * 64 + r) * ldb + kt + ce),
          (__attribute__((address_space(3))) void*)((char*)Bs + c * 16), 16, 0, 0);
    }
    asm volatile("s_waitcnt vmcnt(0)" ::: "memory");
    __syncthreads();
    #pragma unroll
    for (int ks = 0; ks < 4; ++ks) {
      short8 a[2], bfr[2];
      #pragma unroll
      for (int m = 0; m < 2; ++m) {
        const int row = wr * 32 + m * 16 + lr;
        a[m] = *(const short8*)((char*)As + row * 256 + ((((ks * 4 + lk) ^ (row & 15))) * 16));
      }
      #pragma unroll
      for (int n = 0; n < 2; ++n) {
        const int row = wc * 32 + n * 16 + lr;
        bfr[n] = *(const short8*)((char*)Bs + row * 256 + ((((ks * 4 + lk) ^ (row & 15))) * 16));
      }
      #pragma unroll
      for (int m = 0; m < 2; ++m)
        #pragma unroll
        for (int n = 0; n < 2; ++n)
          acc[m][n] = __builtin_amdgcn_mfma_f32_16x16x32_bf16(a[m], bfr[n], acc[m][n], 0, 0, 0);
    }
  }
}

// Q projection: 256 blocks of 64x64
__global__ __launch_bounds__(256) void gemm_q64(
    const short* __restrict__ qx, const short* __restrict__ wqb,
    const float* __restrict__ b_q, short* __restrict__ Qo)
{
  __shared__ __align__(16) short As[64 * 128];
  __shared__ __align__(16) short Bs[64 * 128];
  const int bid = blockIdx.x;
  const int u = (bid & 7) * 32 + (bid >> 3);
  const int mt = u >> 4, nt = u & 15;

  f32x4 acc[2][2] = {};
  gemm64_core(qx, wqb, mt, nt, D_, D_, D_, acc, As, Bs);

  const int l = threadIdx.x & 63, w = threadIdx.x >> 6;
  const int wr = w >> 1, wc = w & 1;
  const int lr = l & 15, lk = l >> 4;
  #pragma unroll
  for (int n = 0; n < 2; ++n) {
    const int col = nt * 64 + wc * 32 + n * 16 + lr;
    const float bv = b_q[col];
    #pragma unroll
    for (int m = 0; m < 2; ++m) {
      const int row0 = mt * 64 + wr * 32 + m * 16 + lk * 4;
      #pragma unroll
      for (int i = 0; i < 4; ++i)
        Qo[(size_t)(row0 + i) * D_ + col] = f2bf(acc[m][n][i] + bv);
    }
  }
}

// ---------------------------------------------------------------------------
// gemm_qt: q~[bp,h,:] = Q[bp, h*64..h*64+63] @ wk[h*64.., :]  (K=64)
// (single K-tile, 1024 blocks = 4/CU; unchanged, measured-fine)
// ---------------------------------------------------------------------------
__global__ __launch_bounds__(256) void gemm_qt(
    const short* __restrict__ Qo, const short* __restrict__ wkT,
    short* __restrict__ Qt)
{
  __shared__ __align__(16) short As[128 * 64];
  __shared__ __align__(16) short Bs[128 * 64];
  const int bid = blockIdx.x;
  const int hh = bid >> 6, mt = (bid >> 3) & 7, nt = bid & 7;
  const int tid = threadIdx.x;
  const int wid = tid >> 6, l = tid & 63;
  const int wr = wid >> 1, wc = wid & 1;
  const int lr = l & 15, lk = l >> 4;
  const int sr = l >> 3, scol = (l & 7) * 8;

  #pragma unroll
  for (int j = 0; j < 4; ++j) {
    const int r = (wid * 4 + j) * 8 + sr;
    __builtin_amdgcn_global_load_lds(
        (const __attribute__((address_space(1))) void*)(Qo + (size_t)(mt * 128 + r) * D_ + hh * 64 + scol),
        (__attribute__((address_space(3))) void*)(As + (wid * 4 + j) * 512), 16, 0, 0);
    __builtin_amdgcn_global_load_lds(
        (const __attribute__((address_space(1))) void*)(wkT + (size_t)(nt * 128 + r) * D_ + hh * 64 + scol),
        (__attribute__((address_space(3))) void*)(Bs + (wid * 4 + j) * 512), 16, 0, 0);
  }
  asm volatile("s_waitcnt vmcnt(0)" ::: "memory");
  __syncthreads();

  f32x4 acc[4][4] = {};
  #pragma unroll
  for (int ks = 0; ks < 2; ++ks) {
    short8 a[4], bfr[4];
    #pragma unroll
    for (int m = 0; m < 4; ++m)
      a[m] = *(const short8*)(As + (wr * 64 + m * 16 + lr) * 64 + ks * 32 + lk * 8);
    #pragma unroll
    for (int n = 0; n < 4; ++n)
      bfr[n] = *(const short8*)(Bs + (wc * 64 + n * 16 + lr) * 64 + ks * 32 + lk * 8);
    #pragma unroll
    for (int m = 0; m < 4; ++m)
      #pragma unroll
      for (int n = 0; n < 4; ++n)
        acc[m][n] = __builtin_amdgcn_mfma_f32_16x16x32_bf16(a[m], bfr[n], acc[m][n], 0, 0, 0);
  }

  #pragma unroll
  for (int n = 0; n < 4; ++n) {
    const int col = nt * 128 + wc * 64 + n * 16 + lr;
    #pragma unroll
    for (int m = 0; m < 4; ++m) {
      const int row0 = mt * 128 + wr * 64 + m * 16 + lk * 4;
      #pragma unroll
      for (int i = 0; i < 4; ++i)
        Qt[((size_t)(row0 + i) * 16 + hh) * D_ + col] = f2bf(acc[m][n][i]);
    }
  }
}

// ---------------------------------------------------------------------------
// attn2 v3 (R10 verbatim, measured 52us): per (b,p) block, 512 threads.
// ---------------------------------------------------------------------------
__global__ __launch_bounds__(512) void attn2_kernel(
    const short* __restrict__ Qt, const float* __restrict__ X,
    const int* __restrict__ pos, const float* __restrict__ mask,
    short* __restrict__ Xbar)
{
  __shared__ __align__(16) short Xs[16 * 1024];   // 32KB, swizzled rows of 2048B
  __shared__ float attnT[16][16];                 // [t][h]
  __shared__ float rband[16];
  __shared__ float denL[16];
  __shared__ __align__(16) float red[8][256];     // 8KB reduce tree

  const int bp = blockIdx.x;
  const int b = bp >> 8;
  const int tid = threadIdx.x;
  const int w = tid >> 6, l = tid & 63;
  const int t_l = l & 15;
  const int lk = l >> 4;
  const int hgrp = lk * 4;

  short8 af[4];
  {
    const short* qb = Qt + ((size_t)bp * 16 + t_l) * D_;
    #pragma unroll
    for (int ks = 0; ks < 4; ++ks)
      af[ks] = *(const short8*)(qb + (w * 4 + ks) * 32 + lk * 8);
  }

  const bool is64 = (pos[1] == 0);
  const int start = is64 ? pos[4 * bp]     : pos[2 * bp];
  const int end   = is64 ? pos[4 * bp + 2] : pos[2 * bp + 1];
  const bool valid = (start < S_) && (end <= S_) && (start < end);
  const int lo = valid ? (start < 0 ? 0 : start) : 0;
  const int hi = valid ? end : 0;

  float xacc[16][2];
  #pragma unroll
  for (int h = 0; h < 16; ++h) { xacc[h][0] = 0.f; xacc[h][1] = 0.f; }
  float m_run[4] = {-3.0e38f, -3.0e38f, -3.0e38f, -3.0e38f};
  float den[4] = {0.f, 0.f, 0.f, 0.f};

  for (int c0 = lo; c0 < hi; c0 += 16) {
    __syncthreads();
    #pragma unroll
    for (int j = 0; j < 16; ++j) {
      int rg = c0 + j; rg = rg < S_ ? rg : S_ - 1;
      const float2 xv = *(const float2*)(X + ((size_t)b * S_ + rg) * D_ + tid * 2);
      short2v o;
      o[0] = f2bf(xv.x); o[1] = f2bf(xv.y);
      *(short2v*)((char*)Xs + j * 2048 + ((tid * 4) ^ ((j & 7) << 4))) = o;
    }
    __syncthreads();

    f32x4 c = {};
    const int rsw = (t_l & 7) << 4;
    #pragma unroll
    for (int ks = 0; ks < 4; ++ks) {
      const int kb = ((w * 4 + ks) * 32 + lk * 8) * 2;
      const short8 x8 = *(const short8*)((char*)Xs + t_l * 2048 + (kb ^ rsw));
      c = __builtin_amdgcn_mfma_f32_16x16x32_bf16(af[ks], x8, c, 0, 0, 0);
    }
    *(f32x4*)&red[w][l * 4] = c;
    __syncthreads();
    f32x4 s = *(const f32x4*)&red[0][l * 4];
    #pragma unroll
    for (int ww = 1; ww < 8; ++ww)
      s = s + *(const f32x4*)&red[ww][l * 4];

    const int tg = c0 + t_l;
    const bool ok = (tg < hi) && (mask[(size_t)b * S_ + tg] != 0.f);
    float wgt[4], rr[4];
    #pragma unroll
    for (int i = 0; i < 4; ++i) {
      const float sc = ok ? s[i] * 0.125f : -3.0e38f;
      float cm = sc;
      cm = fmaxf(cm, __shfl_xor(cm, 1, 64));
      cm = fmaxf(cm, __shfl_xor(cm, 2, 64));
      cm = fmaxf(cm, __shfl_xor(cm, 4, 64));
      cm = fmaxf(cm, __shfl_xor(cm, 8, 64));
      const float nm = fmaxf(m_run[i], cm);
      const float r = __expf(m_run[i] - nm);
      const float wv_ = ok ? __expf(sc - nm) : 0.f;
      float ws = wv_;
      ws += __shfl_xor(ws, 1, 64);
      ws += __shfl_xor(ws, 2, 64);
      ws += __shfl_xor(ws, 4, 64);
      ws += __shfl_xor(ws, 8, 64);
      den[i] = den[i] * r + ws;
      m_run[i] = nm;
      wgt[i] = wv_; rr[i] = r;
    }
    if (w == 0) {
      #pragma unroll
      for (int i = 0; i < 4; ++i) attnT[t_l][hgrp + i] = wgt[i];
      if (t_l == 0) {
        #pragma unroll
        for (int i = 0; i < 4; ++i) rband[hgrp + i] = rr[i];
      }
    }
    __syncthreads();

    #pragma unroll
    for (int h = 0; h < 16; ++h) {
      const float rb = rband[h];
      xacc[h][0] *= rb; xacc[h][1] *= rb;
    }
    #pragma unroll
    for (int t = 0; t < 16; ++t) {
      const f32x4 a0 = *(const f32x4*)&attnT[t][0];
      const f32x4 a1 = *(const f32x4*)&attnT[t][4];
      const f32x4 a2 = *(const f32x4*)&attnT[t][8];
      const f32x4 a3 = *(const f32x4*)&attnT[t][12];
      const short2v xv = *(const short2v*)((char*)Xs + t * 2048 + ((tid * 4) ^ ((t & 7) << 4)));
      const float x0 = b2f(xv[0]), x1 = b2f(xv[1]);
      #pragma unroll
      for (int i = 0; i < 4; ++i) {
        xacc[i][0]      += a0[i] * x0; xacc[i][1]      += a0[i] * x1;
        xacc[i + 4][0]  += a1[i] * x0; xacc[i + 4][1]  += a1[i] * x1;
        xacc[i + 8][0]  += a2[i] * x0; xacc[i + 8][1]  += a2[i] * x1;
        xacc[i + 12][0] += a3[i] * x0; xacc[i + 12][1] += a3[i] * x1;
      }
    }
  }

  if (w == 0 && t_l == 0) {
    #pragma unroll
    for (int i = 0; i < 4; ++i) denL[hgrp + i] = den[i];
  }
  __syncthreads();

  bool need = false;
  #pragma unroll
  for (int h = 0; h < 16; ++h) need = need || (denL[h] <= 0.f);
  float ms[2] = {0.f, 0.f};
  if (need) {
    for (int t = 0; t < S_; ++t) {
      const float2 xv = *(const float2*)(X + ((size_t)b * S_ + t) * D_ + tid * 2);
      ms[0] += xv.x; ms[1] += xv.y;
    }
    ms[0] *= (1.f / S_); ms[1] *= (1.f / S_);
  }
  #pragma unroll
  for (int h = 0; h < 16; ++h) {
    const float dL = denL[h];
    short2v o;
    if (dL > 0.f) {
      const float inv = 1.f / dL;
      o[0] = f2bf(xacc[h][0] * inv); o[1] = f2bf(xacc[h][1] * inv);
    } else {
      o[0] = f2bf(ms[0]); o[1] = f2bf(ms[1]);
    }
    *(short2v*)(Xbar + ((size_t)bp * 16 + h) * D_ + tid * 2) = o;
  }
}

// ---------------------------------------------------------------------------
// gemm_v64: AO[:, h*64..] = xbar_h @ wv_h^T + b_v. 256 blocks (16h x 16mt).
// ---------------------------------------------------------------------------
__global__ __launch_bounds__(256) void gemm_v64(
    const short* __restrict__ Xbar, const short* __restrict__ wvb,
    const float* __restrict__ b_v, short* __restrict__ AO)
{
  __shared__ __align__(16) short As[64 * 128];
  __shared__ __align__(16) short Bs[64 * 128];
  const int bid = blockIdx.x;
  const int u = (bid & 7) * 32 + (bid >> 3);
  const int h = u >> 4, mt = u & 15;

  f32x4 acc[2][2] = {};
  gemm64_core(Xbar + (size_t)h * D_, wvb + (size_t)h * 64 * D_,
              mt, 0, D_, 16 * D_, D_, acc, As, Bs);

  const int l = threadIdx.x & 63, w = threadIdx.x >> 6;
  const int wr = w >> 1, wc = w & 1;
  const int lr = l & 15, lk = l >> 4;
  #pragma unroll
  for (int n = 0; n < 2; ++n) {
    const int gcol = h * 64 + wc * 32 + n * 16 + lr;
    const float bv = b_v[gcol];
    #pragma unroll
    for (int m = 0; m < 2; ++m) {
      const int row0 = mt * 64 + wr * 32 + m * 16 + lk * 4;
      #pragma unroll
      for (int i = 0; i < 4; ++i)
        AO[(size_t)(row0 + i) * D_ + gcol] = f2bf(acc[m][n][i] + bv);
    }
  }
}

// O projection + bias + residual, fp32 out. 256 blocks of 64x64.
__global__ __launch_bounds__(256) void gemm_o64(
    const short* __restrict__ AO, const short* __restrict__ wob,
    const float* __restrict__ b_o, const float* __restrict__ pe,
    float* __restrict__ out)
{
  __shared__ __align__(16) short As[64 * 128];
  __shared__ __align__(16) short Bs[64 * 128];
  const int bid = blockIdx.x;
  const int u = (bid & 7) * 32 + (bid >> 3);
  const int mt = u >> 4, nt = u & 15;

  f32x4 acc[2][2] = {};
  gemm64_core(AO, wob, mt, nt, D_, D_, D_, acc, As, Bs);

  const int l = threadIdx.x & 63, w = threadIdx.x >> 6;
  const int wr = w >> 1, wc = w & 1;
  const int lr = l & 15, lk = l >> 4;
  #pragma unroll
  for (int n = 0; n < 2; ++n) {
    const int col = nt * 64 + wc * 32 + n * 16 + lr;
    const float bv = b_o[col];
    #pragma unroll
    for (int m = 0; m < 2; ++m) {
      const int row0 = mt * 64 + wr * 32 + m * 16 + lk * 4;
      #pragma unroll
      for (int i = 0; i < 4; ++i) {
        const size_t idx = (size_t)(row0 + i) * D_ + col;
        out[idx] = acc[m][n][i] + bv + pe[idx];
      }
    }
  }
}

// ---------------------------------------------------------------------------
extern "C" void kernel_launch(void* const* d_in, const int* in_sizes, int n_in,
                              void* d_out, int out_size, void* d_ws, size_t ws_size,
                              hipStream_t stream)
{
  const float* pe    = (const float*)d_in[0];
  const float* xby   = (const float*)d_in[1];
  const int*   pos   = (const int*)d_in[2];
  const float* mask  = (const float*)d_in[3];
  const float* gamma = (const float*)d_in[4];
  const float* beta  = (const float*)d_in[5];
  const float* w_q   = (const float*)d_in[6];
  const float* b_q   = (const float*)d_in[7];
  const float* w_k   = (const float*)d_in[8];
  const float* b_k   = (const float*)d_in[9];  (void)b_k; // softmax-shift invariant
  const float* w_v   = (const float*)d_in[10];
  const float* b_v   = (const float*)d_in[11];
  const float* w_o   = (const float*)d_in[12];
  const float* b_o   = (const float*)d_in[13];

  char* ws = (char*)d_ws;
  short* Qt   = (short*)(ws);                // 32 MB: q~ [bp*16+h][1024] bf16
  short* Xbar = (short*)(ws + 33554432);     // 32 MB: xbar same layout
  short* wqb  = (short*)(ws + 67108864);     // 2 MB each
  short* wvb  = (short*)(ws + 69206016);
  short* wob  = (short*)(ws + 71303168);
  short* wkT  = (short*)(ws + 73400320);     // 2 MB: wk transposed bf16
  short* qx   = (short*)(ws + 75497472);     // 2 MB: LN(pe) bf16
  short* Qo   = (short*)(ws + 77594624);     // 2 MB: Q bf16
  short* AO   = (short*)(ws + 79691776);     // 2 MB: attention out bf16
  (void)in_sizes; (void)n_in; (void)out_size; (void)ws_size;

  prep2_kernel<<<2624, 256, 0, stream>>>(pe, gamma, beta, w_q, w_k, w_v, w_o,
                                         wqb, wvb, wob, wkT, qx);
  gemm_q64<<<256, 256, 0, stream>>>(qx, wqb, b_q, Qo);
  gemm_qt<<<1024, 256, 0, stream>>>(Qo, wkT, Qt);
  attn2_kernel<<<1024, 512, 0, stream>>>(Qt, xby, pos, mask, Xbar);
  gemm_v64<<<256, 256, 0, stream>>>(Xbar, wvb, b_v, AO);
  gemm_o64<<<256, 256, 0, stream>>>(AO, wob, b_o, pe, (float*)d_out);
}

// Round 20
// 94.271 us; speedup vs baseline: 1.5011x; 1.0213x over previous
//
#include <hip/hip_runtime.h>
#include <hip/hip_bf16.h>
#include <stdint.h>

#define B_ 4
#define P_ 256
#define S_ 4096
#define D_ 1024
#define H_ 16
#define HD_ 64

typedef __attribute__((ext_vector_type(8))) short short8;
typedef __attribute__((ext_vector_type(4))) short short4v;
typedef __attribute__((ext_vector_type(2))) short short2v;
typedef __attribute__((ext_vector_type(4))) float f32x4;

__device__ __forceinline__ float b2f(short s) {
  return __uint_as_float(((unsigned)(unsigned short)s) << 16);
}
__device__ __forceinline__ short f2bf(float f) {
  unsigned u = __float_as_uint(f);
  unsigned r = (u + 0x7fffu + ((u >> 16) & 1u)) >> 16;
  return (short)(unsigned short)r;
}

// ---------------------------------------------------------------------------
// prep2: wq,wv,wo -> bf16; wk -> bf16 TRANSPOSED (wkT); LN(pe) -> qx
// ---------------------------------------------------------------------------
__global__ __launch_bounds__(256) void prep2_kernel(
    const float* __restrict__ pe,
    const float* __restrict__ gamma, const float* __restrict__ beta,
    const float* __restrict__ wq, const float* __restrict__ wk,
    const float* __restrict__ wv, const float* __restrict__ wo,
    short* __restrict__ wqb, short* __restrict__ wvb, short* __restrict__ wob,
    short* __restrict__ wkT, short* __restrict__ qx)
{
  const int bid = blockIdx.x;
  const int tid = threadIdx.x;
  if (bid < 1536) {
    const int wi = bid >> 9;
    const size_t base = (size_t)(bid & 511) * 2048 + (size_t)tid * 8;
    const float* src; short* dst;
    if (wi == 0)      { src = wq; dst = wqb; }
    else if (wi == 1) { src = wv; dst = wvb; }
    else              { src = wo; dst = wob; }
    const float4 f0 = *(const float4*)(src + base);
    const float4 f1 = *(const float4*)(src + base + 4);
    short8 o;
    o[0] = f2bf(f0.x); o[1] = f2bf(f0.y); o[2] = f2bf(f0.z); o[3] = f2bf(f0.w);
    o[4] = f2bf(f1.x); o[5] = f2bf(f1.y); o[6] = f2bf(f1.z); o[7] = f2bf(f1.w);
    *(short8*)(dst + base) = o;
  } else if (bid < 1600) {
    __shared__ short Ts[128][132];
    const int t = bid - 1536;
    const int ti = t >> 3, tj = t & 7;
    #pragma unroll
    for (int j = 0; j < 16; ++j) {
      const int r = j * 8 + (tid >> 5);
      const int c4 = (tid & 31) * 4;
      const float4 v = *(const float4*)(wk + (size_t)(ti * 128 + r) * D_ + tj * 128 + c4);
      short4v o;
      o[0] = f2bf(v.x); o[1] = f2bf(v.y); o[2] = f2bf(v.z); o[3] = f2bf(v.w);
      *(short4v*)(&Ts[r][c4]) = o;
    }
    __syncthreads();
    #pragma unroll
    for (int j = 0; j < 16; ++j) {
      const int c = j * 8 + (tid >> 5);
      const int r4 = (tid & 31) * 4;
      short4v o;
      o[0] = Ts[r4 + 0][c]; o[1] = Ts[r4 + 1][c];
      o[2] = Ts[r4 + 2][c]; o[3] = Ts[r4 + 3][c];
      *(short4v*)(wkT + (size_t)(tj * 128 + c) * D_ + ti * 128 + r4) = o;
    }
  } else {
    const int row = bid - 1600;
    const int c = tid * 4;
    const float4 x = *(const float4*)(pe + (size_t)row * D_ + c);
    float s1 = x.x + x.y + x.z + x.w;
    float s2 = x.x * x.x + x.y * x.y + x.z * x.z + x.w * x.w;
    #pragma unroll
    for (int off = 32; off >= 1; off >>= 1) {
      s1 += __shfl_xor(s1, off, 64);
      s2 += __shfl_xor(s2, off, 64);
    }
    __shared__ float red[8];
    const int wid = tid >> 6, lane = tid & 63;
    if (lane == 0) { red[wid] = s1; red[4 + wid] = s2; }
    __syncthreads();
    s1 = red[0] + red[1] + red[2] + red[3];
    s2 = red[4] + red[5] + red[6] + red[7];
    const float mu = s1 * (1.0f / D_);
    const float var = s2 * (1.0f / D_) - mu * mu;
    const float rs = rsqrtf(var + 1e-5f);
    const float4 g = *(const float4*)(gamma + c);
    const float4 bt = *(const float4*)(beta + c);
    short4v o;
    o[0] = f2bf((x.x - mu) * rs * g.x + bt.x);
    o[1] = f2bf((x.y - mu) * rs * g.y + bt.y);
    o[2] = f2bf((x.z - mu) * rs * g.z + bt.z);
    o[3] = f2bf((x.w - mu) * rs * g.w + bt.w);
    *(short4v*)(qx + (size_t)row * D_ + c) = o;
  }
}

// ---------------------------------------------------------------------------
// 64x64-tile GEMM core, BK=256 (4 K-tiles for K=1024 -> half the vmcnt(0)
// drains of BK=128). 4 waves, 2x2 frags. Both-sides XOR swizzle at 16B
// granules over 32-granule (512B) rows: write chunk c -> linear granule
// (c&31) of row r=c>>5 with pre-swizzled source col ((c&31)^(r&31))*8;
// read granule (ks*4+lk)^(row&31) -> returns K-contiguous source data.
// ---------------------------------------------------------------------------
__device__ __forceinline__ void gemm64_core(
    const short* __restrict__ A, const short* __restrict__ W,
    int mt, int nt, int Kd, int lda, int ldb,
    f32x4 acc[2][2], short* As, short* Bs)
{
  const int tid = threadIdx.x;
  const int w = tid >> 6, l = tid & 63;
  const int wr = w >> 1, wc = w & 1;
  const int lr = l & 15, lk = l >> 4;
  (void)l; (void)w;

  for (int kt = 0; kt < Kd; kt += 256) {
    __syncthreads();
    #pragma unroll
    for (int j = 0; j < 8; ++j) {
      const int c = j * 256 + tid;               // chunk 0..2047 (16B each)
      const int r = c >> 5;                      // tile row 0..63
      const int ce = ((c & 31) ^ (r & 31)) * 8;  // pre-swizzled source col
      __builtin_amdgcn_global_load_lds(
          (const __attribute__((address_space(1))) void*)(A + (size_t)(mt * 64 + r) * lda + kt + ce),
          (__attribute__((address_space(3))) void*)((char*)As + c * 16), 16, 0, 0);
      __builtin_amdgcn_global_load_lds(
          (const __attribute__((address_space(1))) void*)(W + (size_t)(nt * 64 + r) * ldb + kt + ce),
          (__attribute__((address_space(3))) void*)((char*)Bs + c * 16), 16, 0, 0);
    }
    asm volatile("s_waitcnt vmcnt(0)" ::: "memory");
    __syncthreads();
    #pragma unroll
    for (int ks = 0; ks < 8; ++ks) {
      short8 a[2], bfr[2];
      #pragma unroll
      for (int m = 0; m < 2; ++m) {
        const int row = wr * 32 + m * 16 + lr;
        a[m] = *(const short8*)((char*)As + row * 512 + ((((ks * 4 + lk) ^ (row & 31))) * 16));
      }
      #pragma unroll
      for (int n = 0; n < 2; ++n) {
        const int row = wc * 32 + n * 16 + lr;
        bfr[n] = *(const short8*)((char*)Bs + row * 512 + ((((ks * 4 + lk) ^ (row & 31))) * 16));
      }
      #pragma unroll
      for (int m = 0; m < 2; ++m)
        #pragma unroll
        for (int n = 0; n < 2; ++n)
          acc[m][n] = __builtin_amdgcn_mfma_f32_16x16x32_bf16(a[m], bfr[n], acc[m][n], 0, 0, 0);
    }
  }
}

// Q projection: 256 blocks of 64x64
__global__ __launch_bounds__(256) void gemm_q64(
    const short* __restrict__ qx, const short* __restrict__ wqb,
    const float* __restrict__ b_q, short* __restrict__ Qo)
{
  __shared__ __align__(16) short As[64 * 256];
  __shared__ __align__(16) short Bs[64 * 256];
  const int bid = blockIdx.x;
  const int u = (bid & 7) * 32 + (bid >> 3);
  const int mt = u >> 4, nt = u & 15;

  f32x4 acc[2][2] = {};
  gemm64_core(qx, wqb, mt, nt, D_, D_, D_, acc, As, Bs);

  const int l = threadIdx.x & 63, w = threadIdx.x >> 6;
  const int wr = w >> 1, wc = w & 1;
  const int lr = l & 15, lk = l >> 4;
  #pragma unroll
  for (int n = 0; n < 2; ++n) {
    const int col = nt * 64 + wc * 32 + n * 16 + lr;
    const float bv = b_q[col];
    #pragma unroll
    for (int m = 0; m < 2; ++m) {
      const int row0 = mt * 64 + wr * 32 + m * 16 + lk * 4;
      #pragma unroll
      for (int i = 0; i < 4; ++i)
        Qo[(size_t)(row0 + i) * D_ + col] = f2bf(acc[m][n][i] + bv);
    }
  }
}

// ---------------------------------------------------------------------------
// gemm_qt: q~[bp,h,:] = Q[bp, h*64..h*64+63] @ wk[h*64.., :]  (K=64)
// (single K-tile, 1024 blocks = 4/CU; unchanged, measured-fine)
// ---------------------------------------------------------------------------
__global__ __launch_bounds__(256) void gemm_qt(
    const short* __restrict__ Qo, const short* __restrict__ wkT,
    short* __restrict__ Qt)
{
  __shared__ __align__(16) short As[128 * 64];
  __shared__ __align__(16) short Bs[128 * 64];
  const int bid = blockIdx.x;
  const int hh = bid >> 6, mt = (bid >> 3) & 7, nt = bid & 7;
  const int tid = threadIdx.x;
  const int wid = tid >> 6, l = tid & 63;
  const int wr = wid >> 1, wc = wid & 1;
  const int lr = l & 15, lk = l >> 4;
  const int sr = l >> 3, scol = (l & 7) * 8;

  #pragma unroll
  for (int j = 0; j < 4; ++j) {
    const int r = (wid * 4 + j) * 8 + sr;
    __builtin_amdgcn_global_load_lds(
        (const __attribute__((address_space(1))) void*)(Qo + (size_t)(mt * 128 + r) * D_ + hh * 64 + scol),
        (__attribute__((address_space(3))) void*)(As + (wid * 4 + j) * 512), 16, 0, 0);
    __builtin_amdgcn_global_load_lds(
        (const __attribute__((address_space(1))) void*)(wkT + (size_t)(nt * 128 + r) * D_ + hh * 64 + scol),
        (__attribute__((address_space(3))) void*)(Bs + (wid * 4 + j) * 512), 16, 0, 0);
  }
  asm volatile("s_waitcnt vmcnt(0)" ::: "memory");
  __syncthreads();

  f32x4 acc[4][4] = {};
  #pragma unroll
  for (int ks = 0; ks < 2; ++ks) {
    short8 a[4], bfr[4];
    #pragma unroll
    for (int m = 0; m < 4; ++m)
      a[m] = *(const short8*)(As + (wr * 64 + m * 16 + lr) * 64 + ks * 32 + lk * 8);
    #pragma unroll
    for (int n = 0; n < 4; ++n)
      bfr[n] = *(const short8*)(Bs + (wc * 64 + n * 16 + lr) * 64 + ks * 32 + lk * 8);
    #pragma unroll
    for (int m = 0; m < 4; ++m)
      #pragma unroll
      for (int n = 0; n < 4; ++n)
        acc[m][n] = __builtin_amdgcn_mfma_f32_16x16x32_bf16(a[m], bfr[n], acc[m][n], 0, 0, 0);
  }

  #pragma unroll
  for (int n = 0; n < 4; ++n) {
    const int col = nt * 128 + wc * 64 + n * 16 + lr;
    #pragma unroll
    for (int m = 0; m < 4; ++m) {
      const int row0 = mt * 128 + wr * 64 + m * 16 + lk * 4;
      #pragma unroll
      for (int i = 0; i < 4; ++i)
        Qt[((size_t)(row0 + i) * 16 + hh) * D_ + col] = f2bf(acc[m][n][i]);
    }
  }
}

// ---------------------------------------------------------------------------
// attn2 v3 (R10 verbatim, measured 52us): per (b,p) block, 512 threads.
// ---------------------------------------------------------------------------
__global__ __launch_bounds__(512) void attn2_kernel(
    const short* __restrict__ Qt, const float* __restrict__ X,
    const int* __restrict__ pos, const float* __restrict__ mask,
    short* __restrict__ Xbar)
{
  __shared__ __align__(16) short Xs[16 * 1024];   // 32KB, swizzled rows of 2048B
  __shared__ float attnT[16][16];                 // [t][h]
  __shared__ float rband[16];
  __shared__ float denL[16];
  __shared__ __align__(16) float red[8][256];     // 8KB reduce tree

  const int bp = blockIdx.x;
  const int b = bp >> 8;
  const int tid = threadIdx.x;
  const int w = tid >> 6, l = tid & 63;
  const int t_l = l & 15;
  const int lk = l >> 4;
  const int hgrp = lk * 4;

  short8 af[4];
  {
    const short* qb = Qt + ((size_t)bp * 16 + t_l) * D_;
    #pragma unroll
    for (int ks = 0; ks < 4; ++ks)
      af[ks] = *(const short8*)(qb + (w * 4 + ks) * 32 + lk * 8);
  }

  const bool is64 = (pos[1] == 0);
  const int start = is64 ? pos[4 * bp]     : pos[2 * bp];
  const int end   = is64 ? pos[4 * bp + 2] : pos[2 * bp + 1];
  const bool valid = (start < S_) && (end <= S_) && (start < end);
  const int lo = valid ? (start < 0 ? 0 : start) : 0;
  const int hi = valid ? end : 0;

  float xacc[16][2];
  #pragma unroll
  for (int h = 0; h < 16; ++h) { xacc[h][0] = 0.f; xacc[h][1] = 0.f; }
  float m_run[4] = {-3.0e38f, -3.0e38f, -3.0e38f, -3.0e38f};
  float den[4] = {0.f, 0.f, 0.f, 0.f};

  for (int c0 = lo; c0 < hi; c0 += 16) {
    __syncthreads();
    #pragma unroll
    for (int j = 0; j < 16; ++j) {
      int rg = c0 + j; rg = rg < S_ ? rg : S_ - 1;
      const float2 xv = *(const float2*)(X + ((size_t)b * S_ + rg) * D_ + tid * 2);
      short2v o;
      o[0] = f2bf(xv.x); o[1] = f2bf(xv.y);
      *(short2v*)((char*)Xs + j * 2048 + ((tid * 4) ^ ((j & 7) << 4))) = o;
    }
    __syncthreads();

    f32x4 c = {};
    const int rsw = (t_l & 7) << 4;
    #pragma unroll
    for (int ks = 0; ks < 4; ++ks) {
      const int kb = ((w * 4 + ks) * 32 + lk * 8) * 2;
      const short8 x8 = *(const short8*)((char*)Xs + t_l * 2048 + (kb ^ rsw));
      c = __builtin_amdgcn_mfma_f32_16x16x32_bf16(af[ks], x8, c, 0, 0, 0);
    }
    *(f32x4*)&red[w][l * 4] = c;
    __syncthreads();
    f32x4 s = *(const f32x4*)&red[0][l * 4];
    #pragma unroll
    for (int ww = 1; ww < 8; ++ww)
      s = s + *(const f32x4*)&red[ww][l * 4];

    const int tg = c0 + t_l;
    const bool ok = (tg < hi) && (mask[(size_t)b * S_ + tg] != 0.f);
    float wgt[4], rr[4];
    #pragma unroll
    for (int i = 0; i < 4; ++i) {
      const float sc = ok ? s[i] * 0.125f : -3.0e38f;
      float cm = sc;
      cm = fmaxf(cm, __shfl_xor(cm, 1, 64));
      cm = fmaxf(cm, __shfl_xor(cm, 2, 64));
      cm = fmaxf(cm, __shfl_xor(cm, 4, 64));
      cm = fmaxf(cm, __shfl_xor(cm, 8, 64));
      const float nm = fmaxf(m_run[i], cm);
      const float r = __expf(m_run[i] - nm);
      const float wv_ = ok ? __expf(sc - nm) : 0.f;
      float ws = wv_;
      ws += __shfl_xor(ws, 1, 64);
      ws += __shfl_xor(ws, 2, 64);
      ws += __shfl_xor(ws, 4, 64);
      ws += __shfl_xor(ws, 8, 64);
      den[i] = den[i] * r + ws;
      m_run[i] = nm;
      wgt[i] = wv_; rr[i] = r;
    }
    if (w == 0) {
      #pragma unroll
      for (int i = 0; i < 4; ++i) attnT[t_l][hgrp + i] = wgt[i];
      if (t_l == 0) {
        #pragma unroll
        for (int i = 0; i < 4; ++i) rband[hgrp + i] = rr[i];
      }
    }
    __syncthreads();

    #pragma unroll
    for (int h = 0; h < 16; ++h) {
      const float rb = rband[h];
      xacc[h][0] *= rb; xacc[h][1] *= rb;
    }
    #pragma unroll
    for (int t = 0; t < 16; ++t) {
      const f32x4 a0 = *(const f32x4*)&attnT[t][0];
      const f32x4 a1 = *(const f32x4*)&attnT[t][4];
      const f32x4 a2 = *(const f32x4*)&attnT[t][8];
      const f32x4 a3 = *(const f32x4*)&attnT[t][12];
      const short2v xv = *(const short2v*)((char*)Xs + t * 2048 + ((tid * 4) ^ ((t & 7) << 4)));
      const float x0 = b2f(xv[0]), x1 = b2f(xv[1]);
      #pragma unroll
      for (int i = 0; i < 4; ++i) {
        xacc[i][0]      += a0[i] * x0; xacc[i][1]      += a0[i] * x1;
        xacc[i + 4][0]  += a1[i] * x0; xacc[i + 4][1]  += a1[i] * x1;
        xacc[i + 8][0]  += a2[i] * x0; xacc[i + 8][1]  += a2[i] * x1;
        xacc[i + 12][0] += a3[i] * x0; xacc[i + 12][1] += a3[i] * x1;
      }
    }
  }

  if (w == 0 && t_l == 0) {
    #pragma unroll
    for (int i = 0; i < 4; ++i) denL[hgrp + i] = den[i];
  }
  __syncthreads();

  bool need = false;
  #pragma unroll
  for (int h = 0; h < 16; ++h) need = need || (denL[h] <= 0.f);
  float ms[2] = {0.f, 0.f};
  if (need) {
    for (int t = 0; t < S_; ++t) {
      const float2 xv = *(const float2*)(X + ((size_t)b * S_ + t) * D_ + tid * 2);
      ms[0] += xv.x; ms[1] += xv.y;
    }
    ms[0] *= (1.f / S_); ms[1] *= (1.f / S_);
  }
  #pragma unroll
  for (int h = 0; h < 16; ++h) {
    const float dL = denL[h];
    short2v o;
    if (dL > 0.f) {
      const float inv = 1.f / dL;
      o[0] = f2bf(xacc[h][0] * inv); o[1] = f2bf(xacc[h][1] * inv);
    } else {
      o[0] = f2bf(ms[0]); o[1] = f2bf(ms[1]);
    }
    *(short2v*)(Xbar + ((size_t)bp * 16 + h) * D_ + tid * 2) = o;
  }
}

// ---------------------------------------------------------------------------
// gemm_v64: AO[:, h*64..] = xbar_h @ wv_h^T + b_v. 256 blocks (16h x 16mt).
// ---------------------------------------------------------------------------
__global__ __launch_bounds__(256) void gemm_v64(
    const short* __restrict__ Xbar, const short* __restrict__ wvb,
    const float* __restrict__ b_v, short* __restrict__ AO)
{
  __shared__ __align__(16) short As[64 * 256];
  __shared__ __align__(16) short Bs[64 * 256];
  const int bid = blockIdx.x;
  const int u = (bid & 7) * 32 + (bid >> 3);
  const int h = u >> 4, mt = u & 15;

  f32x4 acc[2][2] = {};
  gemm64_core(Xbar + (size_t)h * D_, wvb + (size_t)h * 64 * D_,
              mt, 0, D_, 16 * D_, D_, acc, As, Bs);

  const int l = threadIdx.x & 63, w = threadIdx.x >> 6;
  const int wr = w >> 1, wc = w & 1;
  const int lr = l & 15, lk = l >> 4;
  #pragma unroll
  for (int n = 0; n < 2; ++n) {
    const int gcol = h * 64 + wc * 32 + n * 16 + lr;
    const float bv = b_v[gcol];
    #pragma unroll
    for (int m = 0; m < 2; ++m) {
      const int row0 = mt * 64 + wr * 32 + m * 16 + lk * 4;
      #pragma unroll
      for (int i = 0; i < 4; ++i)
        AO[(size_t)(row0 + i) * D_ + gcol] = f2bf(acc[m][n][i] + bv);
    }
  }
}

// O projection + bias + residual, fp32 out. 256 blocks of 64x64.
__global__ __launch_bounds__(256) void gemm_o64(
    const short* __restrict__ AO, const short* __restrict__ wob,
    const float* __restrict__ b_o, const float* __restrict__ pe,
    float* __restrict__ out)
{
  __shared__ __align__(16) short As[64 * 256];
  __shared__ __align__(16) short Bs[64 * 256];
  const int bid = blockIdx.x;
  const int u = (bid & 7) * 32 + (bid >> 3);
  const int mt = u >> 4, nt = u & 15;

  f32x4 acc[2][2] = {};
  gemm64_core(AO, wob, mt, nt, D_, D_, D_, acc, As, Bs);

  const int l = threadIdx.x & 63, w = threadIdx.x >> 6;
  const int wr = w >> 1, wc = w & 1;
  const int lr = l & 15, lk = l >> 4;
  #pragma unroll
  for (int n = 0; n < 2; ++n) {
    const int col = nt * 64 + wc * 32 + n * 16 + lr;
    const float bv = b_o[col];
    #pragma unroll
    for (int m = 0; m < 2; ++m) {
      const int row0 = mt * 64 + wr * 32 + m * 16 + lk * 4;
      #pragma unroll
      for (int i = 0; i < 4; ++i) {
        const size_t idx = (size_t)(row0 + i) * D_ + col;
        out[idx] = acc[m][n][i] + bv + pe[idx];
      }
    }
  }
}

// ---------------------------------------------------------------------------
extern "C" void kernel_launch(void* const* d_in, const int* in_sizes, int n_in,
                              void* d_out, int out_size, void* d_ws, size_t ws_size,
                              hipStream_t stream)
{
  const float* pe    = (const float*)d_in[0];
  const float* xby   = (const float*)d_in[1];
  const int*   pos   = (const int*)d_in[2];
  const float* mask  = (const float*)d_in[3];
  const float* gamma = (const float*)d_in[4];
  const float* beta  = (const float*)d_in[5];
  const float* w_q   = (const float*)d_in[6];
  const float* b_q   = (const float*)d_in[7];
  const float* w_k   = (const float*)d_in[8];
  const float* b_k   = (const float*)d_in[9];  (void)b_k; // softmax-shift invariant
  const float* w_v   = (const float*)d_in[10];
  const float* b_v   = (const float*)d_in[11];
  const float* w_o   = (const float*)d_in[12];
  const float* b_o   = (const float*)d_in[13];

  char* ws = (char*)d_ws;
  short* Qt   = (short*)(ws);                // 32 MB: q~ [bp*16+h][1024] bf16
  short* Xbar = (short*)(ws + 33554432);     // 32 MB: xbar same layout
  short* wqb  = (short*)(ws + 67108864);     // 2 MB each
  short* wvb  = (short*)(ws + 69206016);
  short* wob  = (short*)(ws + 71303168);
  short* wkT  = (short*)(ws + 73400320);     // 2 MB: wk transposed bf16
  short* qx   = (short*)(ws + 75497472);     // 2 MB: LN(pe) bf16
  short* Qo   = (short*)(ws + 77594624);     // 2 MB: Q bf16
  short* AO   = (short*)(ws + 79691776);     // 2 MB: attention out bf16
  (void)in_sizes; (void)n_in; (void)out_size; (void)ws_size;

  prep2_kernel<<<2624, 256, 0, stream>>>(pe, gamma, beta, w_q, w_k, w_v, w_o,
                                         wqb, wvb, wob, wkT, qx);
  gemm_q64<<<256, 256, 0, stream>>>(qx, wqb, b_q, Qo);
  gemm_qt<<<1024, 256, 0, stream>>>(Qo, wkT, Qt);
  attn2_kernel<<<1024, 512, 0, stream>>>(Qt, xby, pos, mask, Xbar);
  gemm_v64<<<256, 256, 0, stream>>>(Xbar, wvb, b_v, AO);
  gemm_o64<<<256, 256, 0, stream>>>(AO, wob, b_o, pe, (float*)d_out);
}

// Round 21
// 92.944 us; speedup vs baseline: 1.5225x; 1.0143x over previous
//
#include <hip/hip_runtime.h>
#include <hip/hip_bf16.h>
#include <stdint.h>

#define B_ 4
#define P_ 256
#define S_ 4096
#define D_ 1024
#define H_ 16
#define HD_ 64

typedef __attribute__((ext_vector_type(8))) short short8;
typedef __attribute__((ext_vector_type(4))) short short4v;
typedef __attribute__((ext_vector_type(2))) short short2v;
typedef __attribute__((ext_vector_type(4))) float f32x4;

__device__ __forceinline__ float b2f(short s) {
  return __uint_as_float(((unsigned)(unsigned short)s) << 16);
}
__device__ __forceinline__ short f2bf(float f) {
  unsigned u = __float_as_uint(f);
  unsigned r = (u + 0x7fffu + ((u >> 16) & 1u)) >> 16;
  return (short)(unsigned short)r;
}

// ---------------------------------------------------------------------------
// prep2: wq,wv,wo -> bf16; wk -> bf16 TRANSPOSED (wkT); LN(pe) -> qx
// ---------------------------------------------------------------------------
__global__ __launch_bounds__(256) void prep2_kernel(
    const float* __restrict__ pe,
    const float* __restrict__ gamma, const float* __restrict__ beta,
    const float* __restrict__ wq, const float* __restrict__ wk,
    const float* __restrict__ wv, const float* __restrict__ wo,
    short* __restrict__ wqb, short* __restrict__ wvb, short* __restrict__ wob,
    short* __restrict__ wkT, short* __restrict__ qx)
{
  const int bid = blockIdx.x;
  const int tid = threadIdx.x;
  if (bid < 1536) {
    const int wi = bid >> 9;
    const size_t base = (size_t)(bid & 511) * 2048 + (size_t)tid * 8;
    const float* src; short* dst;
    if (wi == 0)      { src = wq; dst = wqb; }
    else if (wi == 1) { src = wv; dst = wvb; }
    else              { src = wo; dst = wob; }
    const float4 f0 = *(const float4*)(src + base);
    const float4 f1 = *(const float4*)(src + base + 4);
    short8 o;
    o[0] = f2bf(f0.x); o[1] = f2bf(f0.y); o[2] = f2bf(f0.z); o[3] = f2bf(f0.w);
    o[4] = f2bf(f1.x); o[5] = f2bf(f1.y); o[6] = f2bf(f1.z); o[7] = f2bf(f1.w);
    *(short8*)(dst + base) = o;
  } else if (bid < 1600) {
    __shared__ short Ts[128][132];
    const int t = bid - 1536;
    const int ti = t >> 3, tj = t & 7;
    #pragma unroll
    for (int j = 0; j < 16; ++j) {
      const int r = j * 8 + (tid >> 5);
      const int c4 = (tid & 31) * 4;
      const float4 v = *(const float4*)(wk + (size_t)(ti * 128 + r) * D_ + tj * 128 + c4);
      short4v o;
      o[0] = f2bf(v.x); o[1] = f2bf(v.y); o[2] = f2bf(v.z); o[3] = f2bf(v.w);
      *(short4v*)(&Ts[r][c4]) = o;
    }
    __syncthreads();
    #pragma unroll
    for (int j = 0; j < 16; ++j) {
      const int c = j * 8 + (tid >> 5);
      const int r4 = (tid & 31) * 4;
      short4v o;
      o[0] = Ts[r4 + 0][c]; o[1] = Ts[r4 + 1][c];
      o[2] = Ts[r4 + 2][c]; o[3] = Ts[r4 + 3][c];
      *(short4v*)(wkT + (size_t)(tj * 128 + c) * D_ + ti * 128 + r4) = o;
    }
  } else {
    const int row = bid - 1600;
    const int c = tid * 4;
    const float4 x = *(const float4*)(pe + (size_t)row * D_ + c);
    float s1 = x.x + x.y + x.z + x.w;
    float s2 = x.x * x.x + x.y * x.y + x.z * x.z + x.w * x.w;
    #pragma unroll
    for (int off = 32; off >= 1; off >>= 1) {
      s1 += __shfl_xor(s1, off, 64);
      s2 += __shfl_xor(s2, off, 64);
    }
    __shared__ float red[8];
    const int wid = tid >> 6, lane = tid & 63;
    if (lane == 0) { red[wid] = s1; red[4 + wid] = s2; }
    __syncthreads();
    s1 = red[0] + red[1] + red[2] + red[3];
    s2 = red[4] + red[5] + red[6] + red[7];
    const float mu = s1 * (1.0f / D_);
    const float var = s2 * (1.0f / D_) - mu * mu;
    const float rs = rsqrtf(var + 1e-5f);
    const float4 g = *(const float4*)(gamma + c);
    const float4 bt = *(const float4*)(beta + c);
    short4v o;
    o[0] = f2bf((x.x - mu) * rs * g.x + bt.x);
    o[1] = f2bf((x.y - mu) * rs * g.y + bt.y);
    o[2] = f2bf((x.z - mu) * rs * g.z + bt.z);
    o[3] = f2bf((x.w - mu) * rs * g.w + bt.w);
    *(short4v*)(qx + (size_t)row * D_ + c) = o;
  }
}

// ---------------------------------------------------------------------------
// 64x64-tile GEMM core, BK=512 (2 K-tiles for K=1024 -> half the vmcnt(0)
// drains of BK=256). 4 waves, 2x2 frags. Both-sides XOR swizzle at 16B
// granules over 64-granule (1024B) rows: write chunk c -> linear granule
// (c&63) of row r=c>>6 with pre-swizzled source col ((c&63)^(r&63))*8;
// read granule (ks*4+lk)^(row&63) -> returns K-contiguous source data.
// ---------------------------------------------------------------------------
__device__ __forceinline__ void gemm64_core(
    const short* __restrict__ A, const short* __restrict__ W,
    int mt, int nt, int Kd, int lda, int ldb,
    f32x4 acc[2][2], short* As, short* Bs)
{
  const int tid = threadIdx.x;
  const int w = tid >> 6, l = tid & 63;
  const int wr = w >> 1, wc = w & 1;
  const int lr = l & 15, lk = l >> 4;
  (void)l; (void)w;

  for (int kt = 0; kt < Kd; kt += 512) {
    __syncthreads();
    #pragma unroll
    for (int j = 0; j < 16; ++j) {
      const int c = j * 256 + tid;               // chunk 0..4095 (16B each)
      const int r = c >> 6;                      // tile row 0..63
      const int ce = ((c & 63) ^ (r & 63)) * 8;  // pre-swizzled source col
      __builtin_amdgcn_global_load_lds(
          (const __attribute__((address_space(1))) void*)(A + (size_t)(mt * 64 + r) * lda + kt + ce),
          (__attribute__((address_space(3))) void*)((char*)As + c * 16), 16, 0, 0);
      __builtin_amdgcn_global_load_lds(
          (const __attribute__((address_space(1))) void*)(W + (size_t)(nt * 64 + r) * ldb + kt + ce),
          (__attribute__((address_space(3))) void*)((char*)Bs + c * 16), 16, 0, 0);
    }
    asm volatile("s_waitcnt vmcnt(0)" ::: "memory");
    __syncthreads();
    #pragma unroll
    for (int ks = 0; ks < 16; ++ks) {
      short8 a[2], bfr[2];
      #pragma unroll
      for (int m = 0; m < 2; ++m) {
        const int row = wr * 32 + m * 16 + lr;
        a[m] = *(const short8*)((char*)As + row * 1024 + ((((ks * 4 + lk) ^ (row & 63))) * 16));
      }
      #pragma unroll
      for (int n = 0; n < 2; ++n) {
        const int row = wc * 32 + n * 16 + lr;
        bfr[n] = *(const short8*)((char*)Bs + row * 1024 + ((((ks * 4 + lk) ^ (row & 63))) * 16));
      }
      #pragma unroll
      for (int m = 0; m < 2; ++m)
        #pragma unroll
        for (int n = 0; n < 2; ++n)
          acc[m][n] = __builtin_amdgcn_mfma_f32_16x16x32_bf16(a[m], bfr[n], acc[m][n], 0, 0, 0);
    }
  }
}

// Q projection: 256 blocks of 64x64
__global__ __launch_bounds__(256) void gemm_q64(
    const short* __restrict__ qx, const short* __restrict__ wqb,
    const float* __restrict__ b_q, short* __restrict__ Qo)
{
  __shared__ __align__(16) short As[64 * 512];
  __shared__ __align__(16) short Bs[64 * 512];
  const int bid = blockIdx.x;
  const int u = (bid & 7) * 32 + (bid >> 3);
  const int mt = u >> 4, nt = u & 15;

  f32x4 acc[2][2] = {};
  gemm64_core(qx, wqb, mt, nt, D_, D_, D_, acc, As, Bs);

  const int l = threadIdx.x & 63, w = threadIdx.x >> 6;
  const int wr = w >> 1, wc = w & 1;
  const int lr = l & 15, lk = l >> 4;
  #pragma unroll
  for (int n = 0; n < 2; ++n) {
    const int col = nt * 64 + wc * 32 + n * 16 + lr;
    const float bv = b_q[col];
    #pragma unroll
    for (int m = 0; m < 2; ++m) {
      const int row0 = mt * 64 + wr * 32 + m * 16 + lk * 4;
      #pragma unroll
      for (int i = 0; i < 4; ++i)
        Qo[(size_t)(row0 + i) * D_ + col] = f2bf(acc[m][n][i] + bv);
    }
  }
}

// ---------------------------------------------------------------------------
// gemm_qt: q~[bp,h,:] = Q[bp, h*64..h*64+63] @ wk[h*64.., :]  (K=64)
// (single K-tile, 1024 blocks = 4/CU; unchanged, measured-fine)
// ---------------------------------------------------------------------------
__global__ __launch_bounds__(256) void gemm_qt(
    const short* __restrict__ Qo, const short* __restrict__ wkT,
    short* __restrict__ Qt)
{
  __shared__ __align__(16) short As[128 * 64];
  __shared__ __align__(16) short Bs[128 * 64];
  const int bid = blockIdx.x;
  const int hh = bid >> 6, mt = (bid >> 3) & 7, nt = bid & 7;
  const int tid = threadIdx.x;
  const int wid = tid >> 6, l = tid & 63;
  const int wr = wid >> 1, wc = wid & 1;
  const int lr = l & 15, lk = l >> 4;
  const int sr = l >> 3, scol = (l & 7) * 8;

  #pragma unroll
  for (int j = 0; j < 4; ++j) {
    const int r = (wid * 4 + j) * 8 + sr;
    __builtin_amdgcn_global_load_lds(
        (const __attribute__((address_space(1))) void*)(Qo + (size_t)(mt * 128 + r) * D_ + hh * 64 + scol),
        (__attribute__((address_space(3))) void*)(As + (wid * 4 + j) * 512), 16, 0, 0);
    __builtin_amdgcn_global_load_lds(
        (const __attribute__((address_space(1))) void*)(wkT + (size_t)(nt * 128 + r) * D_ + hh * 64 + scol),
        (__attribute__((address_space(3))) void*)(Bs + (wid * 4 + j) * 512), 16, 0, 0);
  }
  asm volatile("s_waitcnt vmcnt(0)" ::: "memory");
  __syncthreads();

  f32x4 acc[4][4] = {};
  #pragma unroll
  for (int ks = 0; ks < 2; ++ks) {
    short8 a[4], bfr[4];
    #pragma unroll
    for (int m = 0; m < 4; ++m)
      a[m] = *(const short8*)(As + (wr * 64 + m * 16 + lr) * 64 + ks * 32 + lk * 8);
    #pragma unroll
    for (int n = 0; n < 4; ++n)
      bfr[n] = *(const short8*)(Bs + (wc * 64 + n * 16 + lr) * 64 + ks * 32 + lk * 8);
    #pragma unroll
    for (int m = 0; m < 4; ++m)
      #pragma unroll
      for (int n = 0; n < 4; ++n)
        acc[m][n] = __builtin_amdgcn_mfma_f32_16x16x32_bf16(a[m], bfr[n], acc[m][n], 0, 0, 0);
  }

  #pragma unroll
  for (int n = 0; n < 4; ++n) {
    const int col = nt * 128 + wc * 64 + n * 16 + lr;
    #pragma unroll
    for (int m = 0; m < 4; ++m) {
      const int row0 = mt * 128 + wr * 64 + m * 16 + lk * 4;
      #pragma unroll
      for (int i = 0; i < 4; ++i)
        Qt[((size_t)(row0 + i) * 16 + hh) * D_ + col] = f2bf(acc[m][n][i]);
    }
  }
}

// ---------------------------------------------------------------------------
// attn2 v3 (R10 verbatim, measured 52us): per (b,p) block, 512 threads.
// ---------------------------------------------------------------------------
__global__ __launch_bounds__(512) void attn2_kernel(
    const short* __restrict__ Qt, const float* __restrict__ X,
    const int* __restrict__ pos, const float* __restrict__ mask,
    short* __restrict__ Xbar)
{
  __shared__ __align__(16) short Xs[16 * 1024];   // 32KB, swizzled rows of 2048B
  __shared__ float attnT[16][16];                 // [t][h]
  __shared__ float rband[16];
  __shared__ float denL[16];
  __shared__ __align__(16) float red[8][256];     // 8KB reduce tree

  const int bp = blockIdx.x;
  const int b = bp >> 8;
  const int tid = threadIdx.x;
  const int w = tid >> 6, l = tid & 63;
  const int t_l = l & 15;
  const int lk = l >> 4;
  const int hgrp = lk * 4;

  short8 af[4];
  {
    const short* qb = Qt + ((size_t)bp * 16 + t_l) * D_;
    #pragma unroll
    for (int ks = 0; ks < 4; ++ks)
      af[ks] = *(const short8*)(qb + (w * 4 + ks) * 32 + lk * 8);
  }

  const bool is64 = (pos[1] == 0);
  const int start = is64 ? pos[4 * bp]     : pos[2 * bp];
  const int end   = is64 ? pos[4 * bp + 2] : pos[2 * bp + 1];
  const bool valid = (start < S_) && (end <= S_) && (start < end);
  const int lo = valid ? (start < 0 ? 0 : start) : 0;
  const int hi = valid ? end : 0;

  float xacc[16][2];
  #pragma unroll
  for (int h = 0; h < 16; ++h) { xacc[h][0] = 0.f; xacc[h][1] = 0.f; }
  float m_run[4] = {-3.0e38f, -3.0e38f, -3.0e38f, -3.0e38f};
  float den[4] = {0.f, 0.f, 0.f, 0.f};

  for (int c0 = lo; c0 < hi; c0 += 16) {
    __syncthreads();
    #pragma unroll
    for (int j = 0; j < 16; ++j) {
      int rg = c0 + j; rg = rg < S_ ? rg : S_ - 1;
      const float2 xv = *(const float2*)(X + ((size_t)b * S_ + rg) * D_ + tid * 2);
      short2v o;
      o[0] = f2bf(xv.x); o[1] = f2bf(xv.y);
      *(short2v*)((char*)Xs + j * 2048 + ((tid * 4) ^ ((j & 7) << 4))) = o;
    }
    __syncthreads();

    f32x4 c = {};
    const int rsw = (t_l & 7) << 4;
    #pragma unroll
    for (int ks = 0; ks < 4; ++ks) {
      const int kb = ((w * 4 + ks) * 32 + lk * 8) * 2;
      const short8 x8 = *(const short8*)((char*)Xs + t_l * 2048 + (kb ^ rsw));
      c = __builtin_amdgcn_mfma_f32_16x16x32_bf16(af[ks], x8, c, 0, 0, 0);
    }
    *(f32x4*)&red[w][l * 4] = c;
    __syncthreads();
    f32x4 s = *(const f32x4*)&red[0][l * 4];
    #pragma unroll
    for (int ww = 1; ww < 8; ++ww)
      s = s + *(const f32x4*)&red[ww][l * 4];

    const int tg = c0 + t_l;
    const bool ok = (tg < hi) && (mask[(size_t)b * S_ + tg] != 0.f);
    float wgt[4], rr[4];
    #pragma unroll
    for (int i = 0; i < 4; ++i) {
      const float sc = ok ? s[i] * 0.125f : -3.0e38f;
      float cm = sc;
      cm = fmaxf(cm, __shfl_xor(cm, 1, 64));
      cm = fmaxf(cm, __shfl_xor(cm, 2, 64));
      cm = fmaxf(cm, __shfl_xor(cm, 4, 64));
      cm = fmaxf(cm, __shfl_xor(cm, 8, 64));
      const float nm = fmaxf(m_run[i], cm);
      const float r = __expf(m_run[i] - nm);
      const float wv_ = ok ? __expf(sc - nm) : 0.f;
      float ws = wv_;
      ws += __shfl_xor(ws, 1, 64);
      ws += __shfl_xor(ws, 2, 64);
      ws += __shfl_xor(ws, 4, 64);
      ws += __shfl_xor(ws, 8, 64);
      den[i] = den[i] * r + ws;
      m_run[i] = nm;
      wgt[i] = wv_; rr[i] = r;
    }
    if (w == 0) {
      #pragma unroll
      for (int i = 0; i < 4; ++i) attnT[t_l][hgrp + i] = wgt[i];
      if (t_l == 0) {
        #pragma unroll
        for (int i = 0; i < 4; ++i) rband[hgrp + i] = rr[i];
      }
    }
    __syncthreads();

    #pragma unroll
    for (int h = 0; h < 16; ++h) {
      const float rb = rband[h];
      xacc[h][0] *= rb; xacc[h][1] *= rb;
    }
    #pragma unroll
    for (int t = 0; t < 16; ++t) {
      const f32x4 a0 = *(const f32x4*)&attnT[t][0];
      const f32x4 a1 = *(const f32x4*)&attnT[t][4];
      const f32x4 a2 = *(const f32x4*)&attnT[t][8];
      const f32x4 a3 = *(const f32x4*)&attnT[t][12];
      const short2v xv = *(const short2v*)((char*)Xs + t * 2048 + ((tid * 4) ^ ((t & 7) << 4)));
      const float x0 = b2f(xv[0]), x1 = b2f(xv[1]);
      #pragma unroll
      for (int i = 0; i < 4; ++i) {
        xacc[i][0]      += a0[i] * x0; xacc[i][1]      += a0[i] * x1;
        xacc[i + 4][0]  += a1[i] * x0; xacc[i + 4][1]  += a1[i] * x1;
        xacc[i + 8][0]  += a2[i] * x0; xacc[i + 8][1]  += a2[i] * x1;
        xacc[i + 12][0] += a3[i] * x0; xacc[i + 12][1] += a3[i] * x1;
      }
    }
  }

  if (w == 0 && t_l == 0) {
    #pragma unroll
    for (int i = 0; i < 4; ++i) denL[hgrp + i] = den[i];
  }
  __syncthreads();

  bool need = false;
  #pragma unroll
  for (int h = 0; h < 16; ++h) need = need || (denL[h] <= 0.f);
  float ms[2] = {0.f, 0.f};
  if (need) {
    for (int t = 0; t < S_; ++t) {
      const float2 xv = *(const float2*)(X + ((size_t)b * S_ + t) * D_ + tid * 2);
      ms[0] += xv.x; ms[1] += xv.y;
    }
    ms[0] *= (1.f / S_); ms[1] *= (1.f / S_);
  }
  #pragma unroll
  for (int h = 0; h < 16; ++h) {
    const float dL = denL[h];
    short2v o;
    if (dL > 0.f) {
      const float inv = 1.f / dL;
      o[0] = f2bf(xacc[h][0] * inv); o[1] = f2bf(xacc[h][1] * inv);
    } else {
      o[0] = f2bf(ms[0]); o[1] = f2bf(ms[1]);
    }
    *(short2v*)(Xbar + ((size_t)bp * 16 + h) * D_ + tid * 2) = o;
  }
}

// ---------------------------------------------------------------------------
// gemm_v64: AO[:, h*64..] = xbar_h @ wv_h^T + b_v. 256 blocks (16h x 16mt).
// ---------------------------------------------------------------------------
__global__ __launch_bounds__(256) void gemm_v64(
    const short* __restrict__ Xbar, const short* __restrict__ wvb,
    const float* __restrict__ b_v, short* __restrict__ AO)
{
  __shared__ __align__(16) short As[64 * 512];
  __shared__ __align__(16) short Bs[64 * 512];
  const int bid = blockIdx.x;
  const int u = (bid & 7) * 32 + (bid >> 3);
  const int h = u >> 4, mt = u & 15;

  f32x4 acc[2][2] = {};
  gemm64_core(Xbar + (size_t)h * D_, wvb + (size_t)h * 64 * D_,
              mt, 0, D_, 16 * D_, D_, acc, As, Bs);

  const int l = threadIdx.x & 63, w = threadIdx.x >> 6;
  const int wr = w >> 1, wc = w & 1;
  const int lr = l & 15, lk = l >> 4;
  #pragma unroll
  for (int n = 0; n < 2; ++n) {
    const int gcol = h * 64 + wc * 32 + n * 16 + lr;
    const float bv = b_v[gcol];
    #pragma unroll
    for (int m = 0; m < 2; ++m) {
      const int row0 = mt * 64 + wr * 32 + m * 16 + lk * 4;
      #pragma unroll
      for (int i = 0; i < 4; ++i)
        AO[(size_t)(row0 + i) * D_ + gcol] = f2bf(acc[m][n][i] + bv);
    }
  }
}

// O projection + bias + residual, fp32 out. 256 blocks of 64x64.
__global__ __launch_bounds__(256) void gemm_o64(
    const short* __restrict__ AO, const short* __restrict__ wob,
    const float* __restrict__ b_o, const float* __restrict__ pe,
    float* __restrict__ out)
{
  __shared__ __align__(16) short As[64 * 512];
  __shared__ __align__(16) short Bs[64 * 512];
  const int bid = blockIdx.x;
  const int u = (bid & 7) * 32 + (bid >> 3);
  const int mt = u >> 4, nt = u & 15;

  f32x4 acc[2][2] = {};
  gemm64_core(AO, wob, mt, nt, D_, D_, D_, acc, As, Bs);

  const int l = threadIdx.x & 63, w = threadIdx.x >> 6;
  const int wr = w >> 1, wc = w & 1;
  const int lr = l & 15, lk = l >> 4;
  #pragma unroll
  for (int n = 0; n < 2; ++n) {
    const int col = nt * 64 + wc * 32 + n * 16 + lr;
    const float bv = b_o[col];
    #pragma unroll
    for (int m = 0; m < 2; ++m) {
      const int row0 = mt * 64 + wr * 32 + m * 16 + lk * 4;
      #pragma unroll
      for (int i = 0; i < 4; ++i) {
        const size_t idx = (size_t)(row0 + i) * D_ + col;
        out[idx] = acc[m][n][i] + bv + pe[idx];
      }
    }
  }
}

// ---------------------------------------------------------------------------
extern "C" void kernel_launch(void* const* d_in, const int* in_sizes, int n_in,
                              void* d_out, int out_size, void* d_ws, size_t ws_size,
                              hipStream_t stream)
{
  const float* pe    = (const float*)d_in[0];
  const float* xby   = (const float*)d_in[1];
  const int*   pos   = (const int*)d_in[2];
  const float* mask  = (const float*)d_in[3];
  const float* gamma = (const float*)d_in[4];
  const float* beta  = (const float*)d_in[5];
  const float* w_q   = (const float*)d_in[6];
  const float* b_q   = (const float*)d_in[7];
  const float* w_k   = (const float*)d_in[8];
  const float* b_k   = (const float*)d_in[9];  (void)b_k; // softmax-shift invariant
  const float* w_v   = (const float*)d_in[10];
  const float* b_v   = (const float*)d_in[11];
  const float* w_o   = (const float*)d_in[12];
  const float* b_o   = (const float*)d_in[13];

  char* ws = (char*)d_ws;
  short* Qt   = (short*)(ws);                // 32 MB: q~ [bp*16+h][1024] bf16
  short* Xbar = (short*)(ws + 33554432);     // 32 MB: xbar same layout
  short* wqb  = (short*)(ws + 67108864);     // 2 MB each
  short* wvb  = (short*)(ws + 69206016);
  short* wob  = (short*)(ws + 71303168);
  short* wkT  = (short*)(ws + 73400320);     // 2 MB: wk transposed bf16
  short* qx   = (short*)(ws + 75497472);     // 2 MB: LN(pe) bf16
  short* Qo   = (short*)(ws + 77594624);     // 2 MB: Q bf16
  short* AO   = (short*)(ws + 79691776);     // 2 MB: attention out bf16
  (void)in_sizes; (void)n_in; (void)out_size; (void)ws_size;

  prep2_kernel<<<2624, 256, 0, stream>>>(pe, gamma, beta, w_q, w_k, w_v, w_o,
                                         wqb, wvb, wob, wkT, qx);
  gemm_q64<<<256, 256, 0, stream>>>(qx, wqb, b_q, Qo);
  gemm_qt<<<1024, 256, 0, stream>>>(Qo, wkT, Qt);
  attn2_kernel<<<1024, 512, 0, stream>>>(Qt, xby, pos, mask, Xbar);
  gemm_v64<<<256, 256, 0, stream>>>(Xbar, wvb, b_v, AO);
  gemm_o64<<<256, 256, 0, stream>>>(AO, wob, b_o, pe, (float*)d_out);
}

// Round 22
// 91.942 us; speedup vs baseline: 1.5391x; 1.0109x over previous
//
#include <hip/hip_runtime.h>
#include <hip/hip_bf16.h>
#include <stdint.h>

#define B_ 4
#define P_ 256
#define S_ 4096
#define D_ 1024
#define H_ 16
#define HD_ 64

typedef __attribute__((ext_vector_type(8))) short short8;
typedef __attribute__((ext_vector_type(4))) short short4v;
typedef __attribute__((ext_vector_type(2))) short short2v;
typedef __attribute__((ext_vector_type(4))) float f32x4;

__device__ __forceinline__ float b2f(short s) {
  return __uint_as_float(((unsigned)(unsigned short)s) << 16);
}
__device__ __forceinline__ short f2bf(float f) {
  unsigned u = __float_as_uint(f);
  unsigned r = (u + 0x7fffu + ((u >> 16) & 1u)) >> 16;
  return (short)(unsigned short)r;
}

// ---------------------------------------------------------------------------
// prep2: wq,wv,wo -> bf16; wk -> bf16 TRANSPOSED (wkT); LN(pe) -> qx
// ---------------------------------------------------------------------------
__global__ __launch_bounds__(256) void prep2_kernel(
    const float* __restrict__ pe,
    const float* __restrict__ gamma, const float* __restrict__ beta,
    const float* __restrict__ wq, const float* __restrict__ wk,
    const float* __restrict__ wv, const float* __restrict__ wo,
    short* __restrict__ wqb, short* __restrict__ wvb, short* __restrict__ wob,
    short* __restrict__ wkT, short* __restrict__ qx)
{
  const int bid = blockIdx.x;
  const int tid = threadIdx.x;
  if (bid < 1536) {
    const int wi = bid >> 9;
    const size_t base = (size_t)(bid & 511) * 2048 + (size_t)tid * 8;
    const float* src; short* dst;
    if (wi == 0)      { src = wq; dst = wqb; }
    else if (wi == 1) { src = wv; dst = wvb; }
    else              { src = wo; dst = wob; }
    const float4 f0 = *(const float4*)(src + base);
    const float4 f1 = *(const float4*)(src + base + 4);
    short8 o;
    o[0] = f2bf(f0.x); o[1] = f2bf(f0.y); o[2] = f2bf(f0.z); o[3] = f2bf(f0.w);
    o[4] = f2bf(f1.x); o[5] = f2bf(f1.y); o[6] = f2bf(f1.z); o[7] = f2bf(f1.w);
    *(short8*)(dst + base) = o;
  } else if (bid < 1600) {
    __shared__ short Ts[128][132];
    const int t = bid - 1536;
    const int ti = t >> 3, tj = t & 7;
    #pragma unroll
    for (int j = 0; j < 16; ++j) {
      const int r = j * 8 + (tid >> 5);
      const int c4 = (tid & 31) * 4;
      const float4 v = *(const float4*)(wk + (size_t)(ti * 128 + r) * D_ + tj * 128 + c4);
      short4v o;
      o[0] = f2bf(v.x); o[1] = f2bf(v.y); o[2] = f2bf(v.z); o[3] = f2bf(v.w);
      *(short4v*)(&Ts[r][c4]) = o;
    }
    __syncthreads();
    #pragma unroll
    for (int j = 0; j < 16; ++j) {
      const int c = j * 8 + (tid >> 5);
      const int r4 = (tid & 31) * 4;
      short4v o;
      o[0] = Ts[r4 + 0][c]; o[1] = Ts[r4 + 1][c];
      o[2] = Ts[r4 + 2][c]; o[3] = Ts[r4 + 3][c];
      *(short4v*)(wkT + (size_t)(tj * 128 + c) * D_ + ti * 128 + r4) = o;
    }
  } else {
    const int row = bid - 1600;
    const int c = tid * 4;
    const float4 x = *(const float4*)(pe + (size_t)row * D_ + c);
    float s1 = x.x + x.y + x.z + x.w;
    float s2 = x.x * x.x + x.y * x.y + x.z * x.z + x.w * x.w;
    #pragma unroll
    for (int off = 32; off >= 1; off >>= 1) {
      s1 += __shfl_xor(s1, off, 64);
      s2 += __shfl_xor(s2, off, 64);
    }
    __shared__ float red[8];
    const int wid = tid >> 6, lane = tid & 63;
    if (lane == 0) { red[wid] = s1; red[4 + wid] = s2; }
    __syncthreads();
    s1 = red[0] + red[1] + red[2] + red[3];
    s2 = red[4] + red[5] + red[6] + red[7];
    const float mu = s1 * (1.0f / D_);
    const float var = s2 * (1.0f / D_) - mu * mu;
    const float rs = rsqrtf(var + 1e-5f);
    const float4 g = *(const float4*)(gamma + c);
    const float4 bt = *(const float4*)(beta + c);
    short4v o;
    o[0] = f2bf((x.x - mu) * rs * g.x + bt.x);
    o[1] = f2bf((x.y - mu) * rs * g.y + bt.y);
    o[2] = f2bf((x.z - mu) * rs * g.z + bt.z);
    o[3] = f2bf((x.w - mu) * rs * g.w + bt.w);
    *(short4v*)(qx + (size_t)row * D_ + c) = o;
  }
}

// ---------------------------------------------------------------------------
// 64x64-tile GEMM core, BK=512 (2 K-tiles for K=1024; drain count at LDS
// minimum). 4 waves, 2x2 frags. Both-sides XOR swizzle at 16B granules over
// 64-granule (1024B) rows.
// ---------------------------------------------------------------------------
__device__ __forceinline__ void gemm64_core(
    const short* __restrict__ A, const short* __restrict__ W,
    int mt, int nt, int Kd, int lda, int ldb,
    f32x4 acc[2][2], short* As, short* Bs)
{
  const int tid = threadIdx.x;
  const int w = tid >> 6, l = tid & 63;
  const int wr = w >> 1, wc = w & 1;
  const int lr = l & 15, lk = l >> 4;
  (void)l; (void)w;

  for (int kt = 0; kt < Kd; kt += 512) {
    __syncthreads();
    #pragma unroll
    for (int j = 0; j < 16; ++j) {
      const int c = j * 256 + tid;               // chunk 0..4095 (16B each)
      const int r = c >> 6;                      // tile row 0..63
      const int ce = ((c & 63) ^ (r & 63)) * 8;  // pre-swizzled source col
      __builtin_amdgcn_global_load_lds(
          (const __attribute__((address_space(1))) void*)(A + (size_t)(mt * 64 + r) * lda + kt + ce),
          (__attribute__((address_space(3))) void*)((char*)As + c * 16), 16, 0, 0);
      __builtin_amdgcn_global_load_lds(
          (const __attribute__((address_space(1))) void*)(W + (size_t)(nt * 64 + r) * ldb + kt + ce),
          (__attribute__((address_space(3))) void*)((char*)Bs + c * 16), 16, 0, 0);
    }
    asm volatile("s_waitcnt vmcnt(0)" ::: "memory");
    __syncthreads();
    #pragma unroll
    for (int ks = 0; ks < 16; ++ks) {
      short8 a[2], bfr[2];
      #pragma unroll
      for (int m = 0; m < 2; ++m) {
        const int row = wr * 32 + m * 16 + lr;
        a[m] = *(const short8*)((char*)As + row * 1024 + ((((ks * 4 + lk) ^ (row & 63))) * 16));
      }
      #pragma unroll
      for (int n = 0; n < 2; ++n) {
        const int row = wc * 32 + n * 16 + lr;
        bfr[n] = *(const short8*)((char*)Bs + row * 1024 + ((((ks * 4 + lk) ^ (row & 63))) * 16));
      }
      #pragma unroll
      for (int m = 0; m < 2; ++m)
        #pragma unroll
        for (int n = 0; n < 2; ++n)
          acc[m][n] = __builtin_amdgcn_mfma_f32_16x16x32_bf16(a[m], bfr[n], acc[m][n], 0, 0, 0);
    }
  }
}

// Q projection: 256 blocks of 64x64
__global__ __launch_bounds__(256) void gemm_q64(
    const short* __restrict__ qx, const short* __restrict__ wqb,
    const float* __restrict__ b_q, short* __restrict__ Qo)
{
  __shared__ __align__(16) short As[64 * 512];
  __shared__ __align__(16) short Bs[64 * 512];
  const int bid = blockIdx.x;
  const int u = (bid & 7) * 32 + (bid >> 3);
  const int mt = u >> 4, nt = u & 15;

  f32x4 acc[2][2] = {};
  gemm64_core(qx, wqb, mt, nt, D_, D_, D_, acc, As, Bs);

  const int l = threadIdx.x & 63, w = threadIdx.x >> 6;
  const int wr = w >> 1, wc = w & 1;
  const int lr = l & 15, lk = l >> 4;
  #pragma unroll
  for (int n = 0; n < 2; ++n) {
    const int col = nt * 64 + wc * 32 + n * 16 + lr;
    const float bv = b_q[col];
    #pragma unroll
    for (int m = 0; m < 2; ++m) {
      const int row0 = mt * 64 + wr * 32 + m * 16 + lk * 4;
      #pragma unroll
      for (int i = 0; i < 4; ++i)
        Qo[(size_t)(row0 + i) * D_ + col] = f2bf(acc[m][n][i] + bv);
    }
  }
}

// ---------------------------------------------------------------------------
// gemm_qt: q~[bp,h,:] = Q[bp, h*64..h*64+63] @ wk[h*64.., :]  (K=64)
// T1 XCD swizzle added: u = (bid&7)*128 + (bid>>3) (bijective, 1024%8==0)
// -> each XCD gets a contiguous (hh,mt,nt) chunk; the 8 nt-blocks sharing a
// 32KB Qo A-panel land on ONE XCD's L2 instead of 8 different ones.
// ---------------------------------------------------------------------------
__global__ __launch_bounds__(256) void gemm_qt(
    const short* __restrict__ Qo, const short* __restrict__ wkT,
    short* __restrict__ Qt)
{
  __shared__ __align__(16) short As[128 * 64];
  __shared__ __align__(16) short Bs[128 * 64];
  const int bid = blockIdx.x;
  const int u = (bid & 7) * 128 + (bid >> 3);
  const int hh = u >> 6, mt = (u >> 3) & 7, nt = u & 7;
  const int tid = threadIdx.x;
  const int wid = tid >> 6, l = tid & 63;
  const int wr = wid >> 1, wc = wid & 1;
  const int lr = l & 15, lk = l >> 4;
  const int sr = l >> 3, scol = (l & 7) * 8;

  #pragma unroll
  for (int j = 0; j < 4; ++j) {
    const int r = (wid * 4 + j) * 8 + sr;
    __builtin_amdgcn_global_load_lds(
        (const __attribute__((address_space(1))) void*)(Qo + (size_t)(mt * 128 + r) * D_ + hh * 64 + scol),
        (__attribute__((address_space(3))) void*)(As + (wid * 4 + j) * 512), 16, 0, 0);
    __builtin_amdgcn_global_load_lds(
        (const __attribute__((address_space(1))) void*)(wkT + (size_t)(nt * 128 + r) * D_ + hh * 64 + scol),
        (__attribute__((address_space(3))) void*)(Bs + (wid * 4 + j) * 512), 16, 0, 0);
  }
  asm volatile("s_waitcnt vmcnt(0)" ::: "memory");
  __syncthreads();

  f32x4 acc[4][4] = {};
  #pragma unroll
  for (int ks = 0; ks < 2; ++ks) {
    short8 a[4], bfr[4];
    #pragma unroll
    for (int m = 0; m < 4; ++m)
      a[m] = *(const short8*)(As + (wr * 64 + m * 16 + lr) * 64 + ks * 32 + lk * 8);
    #pragma unroll
    for (int n = 0; n < 4; ++n)
      bfr[n] = *(const short8*)(Bs + (wc * 64 + n * 16 + lr) * 64 + ks * 32 + lk * 8);
    #pragma unroll
    for (int m = 0; m < 4; ++m)
      #pragma unroll
      for (int n = 0; n < 4; ++n)
        acc[m][n] = __builtin_amdgcn_mfma_f32_16x16x32_bf16(a[m], bfr[n], acc[m][n], 0, 0, 0);
  }

  #pragma unroll
  for (int n = 0; n < 4; ++n) {
    const int col = nt * 128 + wc * 64 + n * 16 + lr;
    #pragma unroll
    for (int m = 0; m < 4; ++m) {
      const int row0 = mt * 128 + wr * 64 + m * 16 + lk * 4;
      #pragma unroll
      for (int i = 0; i < 4; ++i)
        Qt[((size_t)(row0 + i) * 16 + hh) * D_ + col] = f2bf(acc[m][n][i]);
    }
  }
}

// ---------------------------------------------------------------------------
// attn2 v3 (R10 verbatim, measured 52us): per (b,p) block, 512 threads.
// ---------------------------------------------------------------------------
__global__ __launch_bounds__(512) void attn2_kernel(
    const short* __restrict__ Qt, const float* __restrict__ X,
    const int* __restrict__ pos, const float* __restrict__ mask,
    short* __restrict__ Xbar)
{
  __shared__ __align__(16) short Xs[16 * 1024];   // 32KB, swizzled rows of 2048B
  __shared__ float attnT[16][16];                 // [t][h]
  __shared__ float rband[16];
  __shared__ float denL[16];
  __shared__ __align__(16) float red[8][256];     // 8KB reduce tree

  const int bp = blockIdx.x;
  const int b = bp >> 8;
  const int tid = threadIdx.x;
  const int w = tid >> 6, l = tid & 63;
  const int t_l = l & 15;
  const int lk = l >> 4;
  const int hgrp = lk * 4;

  short8 af[4];
  {
    const short* qb = Qt + ((size_t)bp * 16 + t_l) * D_;
    #pragma unroll
    for (int ks = 0; ks < 4; ++ks)
      af[ks] = *(const short8*)(qb + (w * 4 + ks) * 32 + lk * 8);
  }

  const bool is64 = (pos[1] == 0);
  const int start = is64 ? pos[4 * bp]     : pos[2 * bp];
  const int end   = is64 ? pos[4 * bp + 2] : pos[2 * bp + 1];
  const bool valid = (start < S_) && (end <= S_) && (start < end);
  const int lo = valid ? (start < 0 ? 0 : start) : 0;
  const int hi = valid ? end : 0;

  float xacc[16][2];
  #pragma unroll
  for (int h = 0; h < 16; ++h) { xacc[h][0] = 0.f; xacc[h][1] = 0.f; }
  float m_run[4] = {-3.0e38f, -3.0e38f, -3.0e38f, -3.0e38f};
  float den[4] = {0.f, 0.f, 0.f, 0.f};

  for (int c0 = lo; c0 < hi; c0 += 16) {
    __syncthreads();
    #pragma unroll
    for (int j = 0; j < 16; ++j) {
      int rg = c0 + j; rg = rg < S_ ? rg : S_ - 1;
      const float2 xv = *(const float2*)(X + ((size_t)b * S_ + rg) * D_ + tid * 2);
      short2v o;
      o[0] = f2bf(xv.x); o[1] = f2bf(xv.y);
      *(short2v*)((char*)Xs + j * 2048 + ((tid * 4) ^ ((j & 7) << 4))) = o;
    }
    __syncthreads();

    f32x4 c = {};
    const int rsw = (t_l & 7) << 4;
    #pragma unroll
    for (int ks = 0; ks < 4; ++ks) {
      const int kb = ((w * 4 + ks) * 32 + lk * 8) * 2;
      const short8 x8 = *(const short8*)((char*)Xs + t_l * 2048 + (kb ^ rsw));
      c = __builtin_amdgcn_mfma_f32_16x16x32_bf16(af[ks], x8, c, 0, 0, 0);
    }
    *(f32x4*)&red[w][l * 4] = c;
    __syncthreads();
    f32x4 s = *(const f32x4*)&red[0][l * 4];
    #pragma unroll
    for (int ww = 1; ww < 8; ++ww)
      s = s + *(const f32x4*)&red[ww][l * 4];

    const int tg = c0 + t_l;
    const bool ok = (tg < hi) && (mask[(size_t)b * S_ + tg] != 0.f);
    float wgt[4], rr[4];
    #pragma unroll
    for (int i = 0; i < 4; ++i) {
      const float sc = ok ? s[i] * 0.125f : -3.0e38f;
      float cm = sc;
      cm = fmaxf(cm, __shfl_xor(cm, 1, 64));
      cm = fmaxf(cm, __shfl_xor(cm, 2, 64));
      cm = fmaxf(cm, __shfl_xor(cm, 4, 64));
      cm = fmaxf(cm, __shfl_xor(cm, 8, 64));
      const float nm = fmaxf(m_run[i], cm);
      const float r = __expf(m_run[i] - nm);
      const float wv_ = ok ? __expf(sc - nm) : 0.f;
      float ws = wv_;
      ws += __shfl_xor(ws, 1, 64);
      ws += __shfl_xor(ws, 2, 64);
      ws += __shfl_xor(ws, 4, 64);
      ws += __shfl_xor(ws, 8, 64);
      den[i] = den[i] * r + ws;
      m_run[i] = nm;
      wgt[i] = wv_; rr[i] = r;
    }
    if (w == 0) {
      #pragma unroll
      for (int i = 0; i < 4; ++i) attnT[t_l][hgrp + i] = wgt[i];
      if (t_l == 0) {
        #pragma unroll
        for (int i = 0; i < 4; ++i) rband[hgrp + i] = rr[i];
      }
    }
    __syncthreads();

    #pragma unroll
    for (int h = 0; h < 16; ++h) {
      const float rb = rband[h];
      xacc[h][0] *= rb; xacc[h][1] *= rb;
    }
    #pragma unroll
    for (int t = 0; t < 16; ++t) {
      const f32x4 a0 = *(const f32x4*)&attnT[t][0];
      const f32x4 a1 = *(const f32x4*)&attnT[t][4];
      const f32x4 a2 = *(const f32x4*)&attnT[t][8];
      const f32x4 a3 = *(const f32x4*)&attnT[t][12];
      const short2v xv = *(const short2v*)((char*)Xs + t * 2048 + ((tid * 4) ^ ((t & 7) << 4)));
      const float x0 = b2f(xv[0]), x1 = b2f(xv[1]);
      #pragma unroll
      for (int i = 0; i < 4; ++i) {
        xacc[i][0]      += a0[i] * x0; xacc[i][1]      += a0[i] * x1;
        xacc[i + 4][0]  += a1[i] * x0; xacc[i + 4][1]  += a1[i] * x1;
        xacc[i + 8][0]  += a2[i] * x0; xacc[i + 8][1]  += a2[i] * x1;
        xacc[i + 12][0] += a3[i] * x0; xacc[i + 12][1] += a3[i] * x1;
      }
    }
  }

  if (w == 0 && t_l == 0) {
    #pragma unroll
    for (int i = 0; i < 4; ++i) denL[hgrp + i] = den[i];
  }
  __syncthreads();

  bool need = false;
  #pragma unroll
  for (int h = 0; h < 16; ++h) need = need || (denL[h] <= 0.f);
  float ms[2] = {0.f, 0.f};
  if (need) {
    for (int t = 0; t < S_; ++t) {
      const float2 xv = *(const float2*)(X + ((size_t)b * S_ + t) * D_ + tid * 2);
      ms[0] += xv.x; ms[1] += xv.y;
    }
    ms[0] *= (1.f / S_); ms[1] *= (1.f / S_);
  }
  #pragma unroll
  for (int h = 0; h < 16; ++h) {
    const float dL = denL[h];
    short2v o;
    if (dL > 0.f) {
      const float inv = 1.f / dL;
      o[0] = f2bf(xacc[h][0] * inv); o[1] = f2bf(xacc[h][1] * inv);
    } else {
      o[0] = f2bf(ms[0]); o[1] = f2bf(ms[1]);
    }
    *(short2v*)(Xbar + ((size_t)bp * 16 + h) * D_ + tid * 2) = o;
  }
}

// ---------------------------------------------------------------------------
// gemm_v64: AO[:, h*64..] = xbar_h @ wv_h^T + b_v. 256 blocks (16h x 16mt).
// ---------------------------------------------------------------------------
__global__ __launch_bounds__(256) void gemm_v64(
    const short* __restrict__ Xbar, const short* __restrict__ wvb,
    const float* __restrict__ b_v, short* __restrict__ AO)
{
  __shared__ __align__(16) short As[64 * 512];
  __shared__ __align__(16) short Bs[64 * 512];
  const int bid = blockIdx.x;
  const int u = (bid & 7) * 32 + (bid >> 3);
  const int h = u >> 4, mt = u & 15;

  f32x4 acc[2][2] = {};
  gemm64_core(Xbar + (size_t)h * D_, wvb + (size_t)h * 64 * D_,
              mt, 0, D_, 16 * D_, D_, acc, As, Bs);

  const int l = threadIdx.x & 63, w = threadIdx.x >> 6;
  const int wr = w >> 1, wc = w & 1;
  const int lr = l & 15, lk = l >> 4;
  #pragma unroll
  for (int n = 0; n < 2; ++n) {
    const int gcol = h * 64 + wc * 32 + n * 16 + lr;
    const float bv = b_v[gcol];
    #pragma unroll
    for (int m = 0; m < 2; ++m) {
      const int row0 = mt * 64 + wr * 32 + m * 16 + lk * 4;
      #pragma unroll
      for (int i = 0; i < 4; ++i)
        AO[(size_t)(row0 + i) * D_ + gcol] = f2bf(acc[m][n][i] + bv);
    }
  }
}

// O projection + bias + residual, fp32 out. 256 blocks of 64x64.
__global__ __launch_bounds__(256) void gemm_o64(
    const short* __restrict__ AO, const short* __restrict__ wob,
    const float* __restrict__ b_o, const float* __restrict__ pe,
    float* __restrict__ out)
{
  __shared__ __align__(16) short As[64 * 512];
  __shared__ __align__(16) short Bs[64 * 512];
  const int bid = blockIdx.x;
  const int u = (bid & 7) * 32 + (bid >> 3);
  const int mt = u >> 4, nt = u & 15;

  f32x4 acc[2][2] = {};
  gemm64_core(AO, wob, mt, nt, D_, D_, D_, acc, As, Bs);

  const int l = threadIdx.x & 63, w = threadIdx.x >> 6;
  const int wr = w >> 1, wc = w & 1;
  const int lr = l & 15, lk = l >> 4;
  #pragma unroll
  for (int n = 0; n < 2; ++n) {
    const int col = nt * 64 + wc * 32 + n * 16 + lr;
    const float bv = b_o[col];
    #pragma unroll
    for (int m = 0; m < 2; ++m) {
      const int row0 = mt * 64 + wr * 32 + m * 16 + lk * 4;
      #pragma unroll
      for (int i = 0; i < 4; ++i) {
        const size_t idx = (size_t)(row0 + i) * D_ + col;
        out[idx] = acc[m][n][i] + bv + pe[idx];
      }
    }
  }
}

// ---------------------------------------------------------------------------
extern "C" void kernel_launch(void* const* d_in, const int* in_sizes, int n_in,
                              void* d_out, int out_size, void* d_ws, size_t ws_size,
                              hipStream_t stream)
{
  const float* pe    = (const float*)d_in[0];
  const float* xby   = (const float*)d_in[1];
  const int*   pos   = (const int*)d_in[2];
  const float* mask  = (const float*)d_in[3];
  const float* gamma = (const float*)d_in[4];
  const float* beta  = (const float*)d_in[5];
  const float* w_q   = (const float*)d_in[6];
  const float* b_q   = (const float*)d_in[7];
  const float* w_k   = (const float*)d_in[8];
  const float* b_k   = (const float*)d_in[9];  (void)b_k; // softmax-shift invariant
  const float* w_v   = (const float*)d_in[10];
  const float* b_v   = (const float*)d_in[11];
  const float* w_o   = (const float*)d_in[12];
  const float* b_o   = (const float*)d_in[13];

  char* ws = (char*)d_ws;
  short* Qt   = (short*)(ws);                // 32 MB: q~ [bp*16+h][1024] bf16
  short* Xbar = (short*)(ws + 33554432);     // 32 MB: xbar same layout
  short* wqb  = (short*)(ws + 67108864);     // 2 MB each
  short* wvb  = (short*)(ws + 69206016);
  short* wob  = (short*)(ws + 71303168);
  short* wkT  = (short*)(ws + 73400320);     // 2 MB: wk transposed bf16
  short* qx   = (short*)(ws + 75497472);     // 2 MB: LN(pe) bf16
  short* Qo   = (short*)(ws + 77594624);     // 2 MB: Q bf16
  short* AO   = (short*)(ws + 79691776);     // 2 MB: attention out bf16
  (void)in_sizes; (void)n_in; (void)out_size; (void)ws_size;

  prep2_kernel<<<2624, 256, 0, stream>>>(pe, gamma, beta, w_q, w_k, w_v, w_o,
                                         wqb, wvb, wob, wkT, qx);
  gemm_q64<<<256, 256, 0, stream>>>(qx, wqb, b_q, Qo);
  gemm_qt<<<1024, 256, 0, stream>>>(Qo, wkT, Qt);
  attn2_kernel<<<1024, 512, 0, stream>>>(Qt, xby, pos, mask, Xbar);
  gemm_v64<<<256, 256, 0, stream>>>(Xbar, wvb, b_v, AO);
  gemm_o64<<<256, 256, 0, stream>>>(AO, wob, b_o, pe, (float*)d_out);
}

// Round 23
// 90.309 us; speedup vs baseline: 1.5669x; 1.0181x over previous
//
#include <hip/hip_runtime.h>
#include <hip/hip_bf16.h>
#include <stdint.h>

#define B_ 4
#define P_ 256
#define S_ 4096
#define D_ 1024
#define H_ 16
#define HD_ 64

typedef __attribute__((ext_vector_type(8))) short short8;
typedef __attribute__((ext_vector_type(4))) short short4v;
typedef __attribute__((ext_vector_type(2))) short short2v;
typedef __attribute__((ext_vector_type(4))) float f32x4;

__device__ __forceinline__ float b2f(short s) {
  return __uint_as_float(((unsigned)(unsigned short)s) << 16);
}
__device__ __forceinline__ short f2bf(float f) {
  unsigned u = __float_as_uint(f);
  unsigned r = (u + 0x7fffu + ((u >> 16) & 1u)) >> 16;
  return (short)(unsigned short)r;
}

// ---------------------------------------------------------------------------
// prep2: wq,wv,wo -> bf16; wk -> bf16 TRANSPOSED (wkT); LN(pe) -> qx
// ---------------------------------------------------------------------------
__global__ __launch_bounds__(256) void prep2_kernel(
    const float* __restrict__ pe,
    const float* __restrict__ gamma, const float* __restrict__ beta,
    const float* __restrict__ wq, const float* __restrict__ wk,
    const float* __restrict__ wv, const float* __restrict__ wo,
    short* __restrict__ wqb, short* __restrict__ wvb, short* __restrict__ wob,
    short* __restrict__ wkT, short* __restrict__ qx)
{
  const int bid = blockIdx.x;
  const int tid = threadIdx.x;
  if (bid < 1536) {
    const int wi = bid >> 9;
    const size_t base = (size_t)(bid & 511) * 2048 + (size_t)tid * 8;
    const float* src; short* dst;
    if (wi == 0)      { src = wq; dst = wqb; }
    else if (wi == 1) { src = wv; dst = wvb; }
    else              { src = wo; dst = wob; }
    const float4 f0 = *(const float4*)(src + base);
    const float4 f1 = *(const float4*)(src + base + 4);
    short8 o;
    o[0] = f2bf(f0.x); o[1] = f2bf(f0.y); o[2] = f2bf(f0.z); o[3] = f2bf(f0.w);
    o[4] = f2bf(f1.x); o[5] = f2bf(f1.y); o[6] = f2bf(f1.z); o[7] = f2bf(f1.w);
    *(short8*)(dst + base) = o;
  } else if (bid < 1600) {
    __shared__ short Ts[128][132];
    const int t = bid - 1536;
    const int ti = t >> 3, tj = t & 7;
    #pragma unroll
    for (int j = 0; j < 16; ++j) {
      const int r = j * 8 + (tid >> 5);
      const int c4 = (tid & 31) * 4;
      const float4 v = *(const float4*)(wk + (size_t)(ti * 128 + r) * D_ + tj * 128 + c4);
      short4v o;
      o[0] = f2bf(v.x); o[1] = f2bf(v.y); o[2] = f2bf(v.z); o[3] = f2bf(v.w);
      *(short4v*)(&Ts[r][c4]) = o;
    }
    __syncthreads();
    #pragma unroll
    for (int j = 0; j < 16; ++j) {
      const int c = j * 8 + (tid >> 5);
      const int r4 = (tid & 31) * 4;
      short4v o;
      o[0] = Ts[r4 + 0][c]; o[1] = Ts[r4 + 1][c];
      o[2] = Ts[r4 + 2][c]; o[3] = Ts[r4 + 3][c];
      *(short4v*)(wkT + (size_t)(tj * 128 + c) * D_ + ti * 128 + r4) = o;
    }
  } else {
    const int row = bid - 1600;
    const int c = tid * 4;
    const float4 x = *(const float4*)(pe + (size_t)row * D_ + c);
    float s1 = x.x + x.y + x.z + x.w;
    float s2 = x.x * x.x + x.y * x.y + x.z * x.z + x.w * x.w;
    #pragma unroll
    for (int off = 32; off >= 1; off >>= 1) {
      s1 += __shfl_xor(s1, off, 64);
      s2 += __shfl_xor(s2, off, 64);
    }
    __shared__ float red[8];
    const int wid = tid >> 6, lane = tid & 63;
    if (lane == 0) { red[wid] = s1; red[4 + wid] = s2; }
    __syncthreads();
    s1 = red[0] + red[1] + red[2] + red[3];
    s2 = red[4] + red[5] + red[6] + red[7];
    const float mu = s1 * (1.0f / D_);
    const float var = s2 * (1.0f / D_) - mu * mu;
    const float rs = rsqrtf(var + 1e-5f);
    const float4 g = *(const float4*)(gamma + c);
    const float4 bt = *(const float4*)(beta + c);
    short4v o;
    o[0] = f2bf((x.x - mu) * rs * g.x + bt.x);
    o[1] = f2bf((x.y - mu) * rs * g.y + bt.y);
    o[2] = f2bf((x.z - mu) * rs * g.z + bt.z);
    o[3] = f2bf((x.w - mu) * rs * g.w + bt.w);
    *(short4v*)(qx + (size_t)row * D_ + c) = o;
  }
}

// ---------------------------------------------------------------------------
// 64x64-tile GEMM core, BK=512 (2 K-tiles for K=1024; drain count at LDS
// minimum). 4 waves, 2x2 frags. Both-sides XOR swizzle at 16B granules over
// 64-granule (1024B) rows.
// ---------------------------------------------------------------------------
__device__ __forceinline__ void gemm64_core(
    const short* __restrict__ A, const short* __restrict__ W,
    int mt, int nt, int Kd, int lda, int ldb,
    f32x4 acc[2][2], short* As, short* Bs)
{
  const int tid = threadIdx.x;
  const int w = tid >> 6, l = tid & 63;
  const int wr = w >> 1, wc = w & 1;
  const int lr = l & 15, lk = l >> 4;
  (void)l; (void)w;

  for (int kt = 0; kt < Kd; kt += 512) {
    __syncthreads();
    #pragma unroll
    for (int j = 0; j < 16; ++j) {
      const int c = j * 256 + tid;               // chunk 0..4095 (16B each)
      const int r = c >> 6;                      // tile row 0..63
      const int ce = ((c & 63) ^ (r & 63)) * 8;  // pre-swizzled source col
      __builtin_amdgcn_global_load_lds(
          (const __attribute__((address_space(1))) void*)(A + (size_t)(mt * 64 + r) * lda + kt + ce),
          (__attribute__((address_space(3))) void*)((char*)As + c * 16), 16, 0, 0);
      __builtin_amdgcn_global_load_lds(
          (const __attribute__((address_space(1))) void*)(W + (size_t)(nt * 64 + r) * ldb + kt + ce),
          (__attribute__((address_space(3))) void*)((char*)Bs + c * 16), 16, 0, 0);
    }
    asm volatile("s_waitcnt vmcnt(0)" ::: "memory");
    __syncthreads();
    #pragma unroll
    for (int ks = 0; ks < 16; ++ks) {
      short8 a[2], bfr[2];
      #pragma unroll
      for (int m = 0; m < 2; ++m) {
        const int row = wr * 32 + m * 16 + lr;
        a[m] = *(const short8*)((char*)As + row * 1024 + ((((ks * 4 + lk) ^ (row & 63))) * 16));
      }
      #pragma unroll
      for (int n = 0; n < 2; ++n) {
        const int row = wc * 32 + n * 16 + lr;
        bfr[n] = *(const short8*)((char*)Bs + row * 1024 + ((((ks * 4 + lk) ^ (row & 63))) * 16));
      }
      #pragma unroll
      for (int m = 0; m < 2; ++m)
        #pragma unroll
        for (int n = 0; n < 2; ++n)
          acc[m][n] = __builtin_amdgcn_mfma_f32_16x16x32_bf16(a[m], bfr[n], acc[m][n], 0, 0, 0);
    }
  }
}

// Q projection: 256 blocks of 64x64
__global__ __launch_bounds__(256) void gemm_q64(
    const short* __restrict__ qx, const short* __restrict__ wqb,
    const float* __restrict__ b_q, short* __restrict__ Qo)
{
  __shared__ __align__(16) short As[64 * 512];
  __shared__ __align__(16) short Bs[64 * 512];
  const int bid = blockIdx.x;
  const int u = (bid & 7) * 32 + (bid >> 3);
  const int mt = u >> 4, nt = u & 15;

  f32x4 acc[2][2] = {};
  gemm64_core(qx, wqb, mt, nt, D_, D_, D_, acc, As, Bs);

  const int l = threadIdx.x & 63, w = threadIdx.x >> 6;
  const int wr = w >> 1, wc = w & 1;
  const int lr = l & 15, lk = l >> 4;
  #pragma unroll
  for (int n = 0; n < 2; ++n) {
    const int col = nt * 64 + wc * 32 + n * 16 + lr;
    const float bv = b_q[col];
    #pragma unroll
    for (int m = 0; m < 2; ++m) {
      const int row0 = mt * 64 + wr * 32 + m * 16 + lk * 4;
      #pragma unroll
      for (int i = 0; i < 4; ++i)
        Qo[(size_t)(row0 + i) * D_ + col] = f2bf(acc[m][n][i] + bv);
    }
  }
}

// ---------------------------------------------------------------------------
// gemm_qt: q~[bp,h,:] = Q[bp, h*64..h*64+63] @ wk[h*64.., :]  (K=64)
// T1 XCD swizzle (R22, measured +1us): u = (bid&7)*128 + (bid>>3).
// ---------------------------------------------------------------------------
__global__ __launch_bounds__(256) void gemm_qt(
    const short* __restrict__ Qo, const short* __restrict__ wkT,
    short* __restrict__ Qt)
{
  __shared__ __align__(16) short As[128 * 64];
  __shared__ __align__(16) short Bs[128 * 64];
  const int bid = blockIdx.x;
  const int u = (bid & 7) * 128 + (bid >> 3);
  const int hh = u >> 6, mt = (u >> 3) & 7, nt = u & 7;
  const int tid = threadIdx.x;
  const int wid = tid >> 6, l = tid & 63;
  const int wr = wid >> 1, wc = wid & 1;
  const int lr = l & 15, lk = l >> 4;
  const int sr = l >> 3, scol = (l & 7) * 8;

  #pragma unroll
  for (int j = 0; j < 4; ++j) {
    const int r = (wid * 4 + j) * 8 + sr;
    __builtin_amdgcn_global_load_lds(
        (const __attribute__((address_space(1))) void*)(Qo + (size_t)(mt * 128 + r) * D_ + hh * 64 + scol),
        (__attribute__((address_space(3))) void*)(As + (wid * 4 + j) * 512), 16, 0, 0);
    __builtin_amdgcn_global_load_lds(
        (const __attribute__((address_space(1))) void*)(wkT + (size_t)(nt * 128 + r) * D_ + hh * 64 + scol),
        (__attribute__((address_space(3))) void*)(Bs + (wid * 4 + j) * 512), 16, 0, 0);
  }
  asm volatile("s_waitcnt vmcnt(0)" ::: "memory");
  __syncthreads();

  f32x4 acc[4][4] = {};
  #pragma unroll
  for (int ks = 0; ks < 2; ++ks) {
    short8 a[4], bfr[4];
    #pragma unroll
    for (int m = 0; m < 4; ++m)
      a[m] = *(const short8*)(As + (wr * 64 + m * 16 + lr) * 64 + ks * 32 + lk * 8);
    #pragma unroll
    for (int n = 0; n < 4; ++n)
      bfr[n] = *(const short8*)(Bs + (wc * 64 + n * 16 + lr) * 64 + ks * 32 + lk * 8);
    #pragma unroll
    for (int m = 0; m < 4; ++m)
      #pragma unroll
      for (int n = 0; n < 4; ++n)
        acc[m][n] = __builtin_amdgcn_mfma_f32_16x16x32_bf16(a[m], bfr[n], acc[m][n], 0, 0, 0);
  }

  #pragma unroll
  for (int n = 0; n < 4; ++n) {
    const int col = nt * 128 + wc * 64 + n * 16 + lr;
    #pragma unroll
    for (int m = 0; m < 4; ++m) {
      const int row0 = mt * 128 + wr * 64 + m * 16 + lk * 4;
      #pragma unroll
      for (int i = 0; i < 4; ++i)
        Qt[((size_t)(row0 + i) * 16 + hh) * D_ + col] = f2bf(acc[m][n][i]);
    }
  }
}

// ---------------------------------------------------------------------------
// attn2b: 512 blocks x 2 patches x 512 threads. Identical per-patch body to
// the measured-best attn2-v3 (52us), looped over 2 patches sequentially with
// full state reset; af reloaded per patch; NO register prefetch across
// patches (R11 spill lesson). Halves block count to amortize per-block
// dispatch/latency fixed costs (occupancy counter showed <1 block/CU avg).
// ---------------------------------------------------------------------------
__global__ __launch_bounds__(512) void attn2_kernel(
    const short* __restrict__ Qt, const float* __restrict__ X,
    const int* __restrict__ pos, const float* __restrict__ mask,
    short* __restrict__ Xbar)
{
  __shared__ __align__(16) short Xs[16 * 1024];   // 32KB, swizzled rows of 2048B
  __shared__ float attnT[16][16];                 // [t][h]
  __shared__ float rband[16];
  __shared__ float denL[16];
  __shared__ __align__(16) float red[8][256];     // 8KB reduce tree

  const int bp0 = blockIdx.x * 2;
  const int b = bp0 >> 8;                          // pairs never cross batch
  const int tid = threadIdx.x;
  const int w = tid >> 6, l = tid & 63;
  const int t_l = l & 15;
  const int lk = l >> 4;
  const int hgrp = lk * 4;

  const bool is64 = (pos[1] == 0);

  for (int p = 0; p < 2; ++p) {
    const int bp = bp0 + p;

    short8 af[4];
    {
      const short* qb = Qt + ((size_t)bp * 16 + t_l) * D_;
      #pragma unroll
      for (int ks = 0; ks < 4; ++ks)
        af[ks] = *(const short8*)(qb + (w * 4 + ks) * 32 + lk * 8);
    }

    const int start = is64 ? pos[4 * bp]     : pos[2 * bp];
    const int end   = is64 ? pos[4 * bp + 2] : pos[2 * bp + 1];
    const bool valid = (start < S_) && (end <= S_) && (start < end);
    const int lo = valid ? (start < 0 ? 0 : start) : 0;
    const int hi = valid ? end : 0;

    float xacc[16][2];
    #pragma unroll
    for (int h = 0; h < 16; ++h) { xacc[h][0] = 0.f; xacc[h][1] = 0.f; }
    float m_run[4] = {-3.0e38f, -3.0e38f, -3.0e38f, -3.0e38f};
    float den[4] = {0.f, 0.f, 0.f, 0.f};

    for (int c0 = lo; c0 < hi; c0 += 16) {
      __syncthreads();   // guards Xs/attnT/denL reuse across chunks AND patches
      #pragma unroll
      for (int j = 0; j < 16; ++j) {
        int rg = c0 + j; rg = rg < S_ ? rg : S_ - 1;
        const float2 xv = *(const float2*)(X + ((size_t)b * S_ + rg) * D_ + tid * 2);
        short2v o;
        o[0] = f2bf(xv.x); o[1] = f2bf(xv.y);
        *(short2v*)((char*)Xs + j * 2048 + ((tid * 4) ^ ((j & 7) << 4))) = o;
      }
      __syncthreads();

      f32x4 c = {};
      const int rsw = (t_l & 7) << 4;
      #pragma unroll
      for (int ks = 0; ks < 4; ++ks) {
        const int kb = ((w * 4 + ks) * 32 + lk * 8) * 2;
        const short8 x8 = *(const short8*)((char*)Xs + t_l * 2048 + (kb ^ rsw));
        c = __builtin_amdgcn_mfma_f32_16x16x32_bf16(af[ks], x8, c, 0, 0, 0);
      }
      *(f32x4*)&red[w][l * 4] = c;
      __syncthreads();
      f32x4 s = *(const f32x4*)&red[0][l * 4];
      #pragma unroll
      for (int ww = 1; ww < 8; ++ww)
        s = s + *(const f32x4*)&red[ww][l * 4];

      const int tg = c0 + t_l;
      const bool ok = (tg < hi) && (mask[(size_t)b * S_ + tg] != 0.f);
      float wgt[4], rr[4];
      #pragma unroll
      for (int i = 0; i < 4; ++i) {
        const float sc = ok ? s[i] * 0.125f : -3.0e38f;
        float cm = sc;
        cm = fmaxf(cm, __shfl_xor(cm, 1, 64));
        cm = fmaxf(cm, __shfl_xor(cm, 2, 64));
        cm = fmaxf(cm, __shfl_xor(cm, 4, 64));
        cm = fmaxf(cm, __shfl_xor(cm, 8, 64));
        const float nm = fmaxf(m_run[i], cm);
        const float r = __expf(m_run[i] - nm);
        const float wv_ = ok ? __expf(sc - nm) : 0.f;
        float ws = wv_;
        ws += __shfl_xor(ws, 1, 64);
        ws += __shfl_xor(ws, 2, 64);
        ws += __shfl_xor(ws, 4, 64);
        ws += __shfl_xor(ws, 8, 64);
        den[i] = den[i] * r + ws;
        m_run[i] = nm;
        wgt[i] = wv_; rr[i] = r;
      }
      if (w == 0) {
        #pragma unroll
        for (int i = 0; i < 4; ++i) attnT[t_l][hgrp + i] = wgt[i];
        if (t_l == 0) {
          #pragma unroll
          for (int i = 0; i < 4; ++i) rband[hgrp + i] = rr[i];
        }
      }
      __syncthreads();

      #pragma unroll
      for (int h = 0; h < 16; ++h) {
        const float rb = rband[h];
        xacc[h][0] *= rb; xacc[h][1] *= rb;
      }
      #pragma unroll
      for (int t = 0; t < 16; ++t) {
        const f32x4 a0 = *(const f32x4*)&attnT[t][0];
        const f32x4 a1 = *(const f32x4*)&attnT[t][4];
        const f32x4 a2 = *(const f32x4*)&attnT[t][8];
        const f32x4 a3 = *(const f32x4*)&attnT[t][12];
        const short2v xv = *(const short2v*)((char*)Xs + t * 2048 + ((tid * 4) ^ ((t & 7) << 4)));
        const float x0 = b2f(xv[0]), x1 = b2f(xv[1]);
        #pragma unroll
        for (int i = 0; i < 4; ++i) {
          xacc[i][0]      += a0[i] * x0; xacc[i][1]      += a0[i] * x1;
          xacc[i + 4][0]  += a1[i] * x0; xacc[i + 4][1]  += a1[i] * x1;
          xacc[i + 8][0]  += a2[i] * x0; xacc[i + 8][1]  += a2[i] * x1;
          xacc[i + 12][0] += a3[i] * x0; xacc[i + 12][1] += a3[i] * x1;
        }
      }
    }

    __syncthreads();   // prior patch's denL reads done before overwrite
    if (w == 0 && t_l == 0) {
      #pragma unroll
      for (int i = 0; i < 4; ++i) denL[hgrp + i] = den[i];
    }
    __syncthreads();

    bool need = false;
    #pragma unroll
    for (int h = 0; h < 16; ++h) need = need || (denL[h] <= 0.f);
    float ms[2] = {0.f, 0.f};
    if (need) {
      for (int t = 0; t < S_; ++t) {
        const float2 xv = *(const float2*)(X + ((size_t)b * S_ + t) * D_ + tid * 2);
        ms[0] += xv.x; ms[1] += xv.y;
      }
      ms[0] *= (1.f / S_); ms[1] *= (1.f / S_);
    }
    #pragma unroll
    for (int h = 0; h < 16; ++h) {
      const float dL = denL[h];
      short2v o;
      if (dL > 0.f) {
        const float inv = 1.f / dL;
        o[0] = f2bf(xacc[h][0] * inv); o[1] = f2bf(xacc[h][1] * inv);
      } else {
        o[0] = f2bf(ms[0]); o[1] = f2bf(ms[1]);
      }
      *(short2v*)(Xbar + ((size_t)bp * 16 + h) * D_ + tid * 2) = o;
    }
  }
}

// ---------------------------------------------------------------------------
// gemm_v64: AO[:, h*64..] = xbar_h @ wv_h^T + b_v. 256 blocks (16h x 16mt).
// ---------------------------------------------------------------------------
__global__ __launch_bounds__(256) void gemm_v64(
    const short* __restrict__ Xbar, const short* __restrict__ wvb,
    const float* __restrict__ b_v, short* __restrict__ AO)
{
  __shared__ __align__(16) short As[64 * 512];
  __shared__ __align__(16) short Bs[64 * 512];
  const int bid = blockIdx.x;
  const int u = (bid & 7) * 32 + (bid >> 3);
  const int h = u >> 4, mt = u & 15;

  f32x4 acc[2][2] = {};
  gemm64_core(Xbar + (size_t)h * D_, wvb + (size_t)h * 64 * D_,
              mt, 0, D_, 16 * D_, D_, acc, As, Bs);

  const int l = threadIdx.x & 63, w = threadIdx.x >> 6;
  const int wr = w >> 1, wc = w & 1;
  const int lr = l & 15, lk = l >> 4;
  #pragma unroll
  for (int n = 0; n < 2; ++n) {
    const int gcol = h * 64 + wc * 32 + n * 16 + lr;
    const float bv = b_v[gcol];
    #pragma unroll
    for (int m = 0; m < 2; ++m) {
      const int row0 = mt * 64 + wr * 32 + m * 16 + lk * 4;
      #pragma unroll
      for (int i = 0; i < 4; ++i)
        AO[(size_t)(row0 + i) * D_ + gcol] = f2bf(acc[m][n][i] + bv);
    }
  }
}

// O projection + bias + residual, fp32 out. 256 blocks of 64x64.
__global__ __launch_bounds__(256) void gemm_o64(
    const short* __restrict__ AO, const short* __restrict__ wob,
    const float* __restrict__ b_o, const float* __restrict__ pe,
    float* __restrict__ out)
{
  __shared__ __align__(16) short As[64 * 512];
  __shared__ __align__(16) short Bs[64 * 512];
  const int bid = blockIdx.x;
  const int u = (bid & 7) * 32 + (bid >> 3);
  const int mt = u >> 4, nt = u & 15;

  f32x4 acc[2][2] = {};
  gemm64_core(AO, wob, mt, nt, D_, D_, D_, acc, As, Bs);

  const int l = threadIdx.x & 63, w = threadIdx.x >> 6;
  const int wr = w >> 1, wc = w & 1;
  const int lr = l & 15, lk = l >> 4;
  #pragma unroll
  for (int n = 0; n < 2; ++n) {
    const int col = nt * 64 + wc * 32 + n * 16 + lr;
    const float bv = b_o[col];
    #pragma unroll
    for (int m = 0; m < 2; ++m) {
      const int row0 = mt * 64 + wr * 32 + m * 16 + lk * 4;
      #pragma unroll
      for (int i = 0; i < 4; ++i) {
        const size_t idx = (size_t)(row0 + i) * D_ + col;
        out[idx] = acc[m][n][i] + bv + pe[idx];
      }
    }
  }
}

// ---------------------------------------------------------------------------
extern "C" void kernel_launch(void* const* d_in, const int* in_sizes, int n_in,
                              void* d_out, int out_size, void* d_ws, size_t ws_size,
                              hipStream_t stream)
{
  const float* pe    = (const float*)d_in[0];
  const float* xby   = (const float*)d_in[1];
  const int*   pos   = (const int*)d_in[2];
  const float* mask  = (const float*)d_in[3];
  const float* gamma = (const float*)d_in[4];
  const float* beta  = (const float*)d_in[5];
  const float* w_q   = (const float*)d_in[6];
  const float* b_q   = (const float*)d_in[7];
  const float* w_k   = (const float*)d_in[8];
  const float* b_k   = (const float*)d_in[9];  (void)b_k; // softmax-shift invariant
  const float* w_v   = (const float*)d_in[10];
  const float* b_v   = (const float*)d_in[11];
  const float* w_o   = (const float*)d_in[12];
  const float* b_o   = (const float*)d_in[13];

  char* ws = (char*)d_ws;
  short* Qt   = (short*)(ws);                // 32 MB: q~ [bp*16+h][1024] bf16
  short* Xbar = (short*)(ws + 33554432);     // 32 MB: xbar same layout
  short* wqb  = (short*)(ws + 67108864);     // 2 MB each
  short* wvb  = (short*)(ws + 69206016);
  short* wob  = (short*)(ws + 71303168);
  short* wkT  = (short*)(ws + 73400320);     // 2 MB: wk transposed bf16
  short* qx   = (short*)(ws + 75497472);     // 2 MB: LN(pe) bf16
  short* Qo   = (short*)(ws + 77594624);     // 2 MB: Q bf16
  short* AO   = (short*)(ws + 79691776);     // 2 MB: attention out bf16
  (void)in_sizes; (void)n_in; (void)out_size; (void)ws_size;

  prep2_kernel<<<2624, 256, 0, stream>>>(pe, gamma, beta, w_q, w_k, w_v, w_o,
                                         wqb, wvb, wob, wkT, qx);
  gemm_q64<<<256, 256, 0, stream>>>(qx, wqb, b_q, Qo);
  gemm_qt<<<1024, 256, 0, stream>>>(Qo, wkT, Qt);
  attn2_kernel<<<512, 512, 0, stream>>>(Qt, xby, pos, mask, Xbar);
  gemm_v64<<<256, 256, 0, stream>>>(Xbar, wvb, b_v, AO);
  gemm_o64<<<256, 256, 0, stream>>>(AO, wob, b_o, pe, (float*)d_out);
}

// Round 24
// 89.539 us; speedup vs baseline: 1.5804x; 1.0086x over previous
//
#include <hip/hip_runtime.h>
#include <hip/hip_bf16.h>
#include <stdint.h>

#define B_ 4
#define P_ 256
#define S_ 4096
#define D_ 1024
#define H_ 16
#define HD_ 64

typedef __attribute__((ext_vector_type(8))) short short8;
typedef __attribute__((ext_vector_type(4))) short short4v;
typedef __attribute__((ext_vector_type(2))) short short2v;
typedef __attribute__((ext_vector_type(4))) float f32x4;

__device__ __forceinline__ float b2f(short s) {
  return __uint_as_float(((unsigned)(unsigned short)s) << 16);
}
__device__ __forceinline__ short f2bf(float f) {
  unsigned u = __float_as_uint(f);
  unsigned r = (u + 0x7fffu + ((u >> 16) & 1u)) >> 16;
  return (short)(unsigned short)r;
}

// ---------------------------------------------------------------------------
// prep2: wq,wv,wo -> bf16; wk -> bf16 TRANSPOSED (wkT); LN(pe) -> qx
// ---------------------------------------------------------------------------
__global__ __launch_bounds__(256) void prep2_kernel(
    const float* __restrict__ pe,
    const float* __restrict__ gamma, const float* __restrict__ beta,
    const float* __restrict__ wq, const float* __restrict__ wk,
    const float* __restrict__ wv, const float* __restrict__ wo,
    short* __restrict__ wqb, short* __restrict__ wvb, short* __restrict__ wob,
    short* __restrict__ wkT, short* __restrict__ qx)
{
  const int bid = blockIdx.x;
  const int tid = threadIdx.x;
  if (bid < 1536) {
    const int wi = bid >> 9;
    const size_t base = (size_t)(bid & 511) * 2048 + (size_t)tid * 8;
    const float* src; short* dst;
    if (wi == 0)      { src = wq; dst = wqb; }
    else if (wi == 1) { src = wv; dst = wvb; }
    else              { src = wo; dst = wob; }
    const float4 f0 = *(const float4*)(src + base);
    const float4 f1 = *(const float4*)(src + base + 4);
    short8 o;
    o[0] = f2bf(f0.x); o[1] = f2bf(f0.y); o[2] = f2bf(f0.z); o[3] = f2bf(f0.w);
    o[4] = f2bf(f1.x); o[5] = f2bf(f1.y); o[6] = f2bf(f1.z); o[7] = f2bf(f1.w);
    *(short8*)(dst + base) = o;
  } else if (bid < 1600) {
    __shared__ short Ts[128][132];
    const int t = bid - 1536;
    const int ti = t >> 3, tj = t & 7;
    #pragma unroll
    for (int j = 0; j < 16; ++j) {
      const int r = j * 8 + (tid >> 5);
      const int c4 = (tid & 31) * 4;
      const float4 v = *(const float4*)(wk + (size_t)(ti * 128 + r) * D_ + tj * 128 + c4);
      short4v o;
      o[0] = f2bf(v.x); o[1] = f2bf(v.y); o[2] = f2bf(v.z); o[3] = f2bf(v.w);
      *(short4v*)(&Ts[r][c4]) = o;
    }
    __syncthreads();
    #pragma unroll
    for (int j = 0; j < 16; ++j) {
      const int c = j * 8 + (tid >> 5);
      const int r4 = (tid & 31) * 4;
      short4v o;
      o[0] = Ts[r4 + 0][c]; o[1] = Ts[r4 + 1][c];
      o[2] = Ts[r4 + 2][c]; o[3] = Ts[r4 + 3][c];
      *(short4v*)(wkT + (size_t)(tj * 128 + c) * D_ + ti * 128 + r4) = o;
    }
  } else {
    const int row = bid - 1600;
    const int c = tid * 4;
    const float4 x = *(const float4*)(pe + (size_t)row * D_ + c);
    float s1 = x.x + x.y + x.z + x.w;
    float s2 = x.x * x.x + x.y * x.y + x.z * x.z + x.w * x.w;
    #pragma unroll
    for (int off = 32; off >= 1; off >>= 1) {
      s1 += __shfl_xor(s1, off, 64);
      s2 += __shfl_xor(s2, off, 64);
    }
    __shared__ float red[8];
    const int wid = tid >> 6, lane = tid & 63;
    if (lane == 0) { red[wid] = s1; red[4 + wid] = s2; }
    __syncthreads();
    s1 = red[0] + red[1] + red[2] + red[3];
    s2 = red[4] + red[5] + red[6] + red[7];
    const float mu = s1 * (1.0f / D_);
    const float var = s2 * (1.0f / D_) - mu * mu;
    const float rs = rsqrtf(var + 1e-5f);
    const float4 g = *(const float4*)(gamma + c);
    const float4 bt = *(const float4*)(beta + c);
    short4v o;
    o[0] = f2bf((x.x - mu) * rs * g.x + bt.x);
    o[1] = f2bf((x.y - mu) * rs * g.y + bt.y);
    o[2] = f2bf((x.z - mu) * rs * g.z + bt.z);
    o[3] = f2bf((x.w - mu) * rs * g.w + bt.w);
    *(short4v*)(qx + (size_t)row * D_ + c) = o;
  }
}

// ---------------------------------------------------------------------------
// 64x64-tile GEMM core, BK=512 (2 K-tiles for K=1024; drain count at LDS
// minimum). 4 waves, 2x2 frags. Both-sides XOR swizzle at 16B granules over
// 64-granule (1024B) rows.
// ---------------------------------------------------------------------------
__device__ __forceinline__ void gemm64_core(
    const short* __restrict__ A, const short* __restrict__ W,
    int mt, int nt, int Kd, int lda, int ldb,
    f32x4 acc[2][2], short* As, short* Bs)
{
  const int tid = threadIdx.x;
  const int w = tid >> 6, l = tid & 63;
  const int wr = w >> 1, wc = w & 1;
  const int lr = l & 15, lk = l >> 4;
  (void)l; (void)w;

  for (int kt = 0; kt < Kd; kt += 512) {
    __syncthreads();
    #pragma unroll
    for (int j = 0; j < 16; ++j) {
      const int c = j * 256 + tid;               // chunk 0..4095 (16B each)
      const int r = c >> 6;                      // tile row 0..63
      const int ce = ((c & 63) ^ (r & 63)) * 8;  // pre-swizzled source col
      __builtin_amdgcn_global_load_lds(
          (const __attribute__((address_space(1))) void*)(A + (size_t)(mt * 64 + r) * lda + kt + ce),
          (__attribute__((address_space(3))) void*)((char*)As + c * 16), 16, 0, 0);
      __builtin_amdgcn_global_load_lds(
          (const __attribute__((address_space(1))) void*)(W + (size_t)(nt * 64 + r) * ldb + kt + ce),
          (__attribute__((address_space(3))) void*)((char*)Bs + c * 16), 16, 0, 0);
    }
    asm volatile("s_waitcnt vmcnt(0)" ::: "memory");
    __syncthreads();
    #pragma unroll
    for (int ks = 0; ks < 16; ++ks) {
      short8 a[2], bfr[2];
      #pragma unroll
      for (int m = 0; m < 2; ++m) {
        const int row = wr * 32 + m * 16 + lr;
        a[m] = *(const short8*)((char*)As + row * 1024 + ((((ks * 4 + lk) ^ (row & 63))) * 16));
      }
      #pragma unroll
      for (int n = 0; n < 2; ++n) {
        const int row = wc * 32 + n * 16 + lr;
        bfr[n] = *(const short8*)((char*)Bs + row * 1024 + ((((ks * 4 + lk) ^ (row & 63))) * 16));
      }
      #pragma unroll
      for (int m = 0; m < 2; ++m)
        #pragma unroll
        for (int n = 0; n < 2; ++n)
          acc[m][n] = __builtin_amdgcn_mfma_f32_16x16x32_bf16(a[m], bfr[n], acc[m][n], 0, 0, 0);
    }
  }
}

// Q projection: 256 blocks of 64x64
__global__ __launch_bounds__(256) void gemm_q64(
    const short* __restrict__ qx, const short* __restrict__ wqb,
    const float* __restrict__ b_q, short* __restrict__ Qo)
{
  __shared__ __align__(16) short As[64 * 512];
  __shared__ __align__(16) short Bs[64 * 512];
  const int bid = blockIdx.x;
  const int u = (bid & 7) * 32 + (bid >> 3);
  const int mt = u >> 4, nt = u & 15;

  f32x4 acc[2][2] = {};
  gemm64_core(qx, wqb, mt, nt, D_, D_, D_, acc, As, Bs);

  const int l = threadIdx.x & 63, w = threadIdx.x >> 6;
  const int wr = w >> 1, wc = w & 1;
  const int lr = l & 15, lk = l >> 4;
  #pragma unroll
  for (int n = 0; n < 2; ++n) {
    const int col = nt * 64 + wc * 32 + n * 16 + lr;
    const float bv = b_q[col];
    #pragma unroll
    for (int m = 0; m < 2; ++m) {
      const int row0 = mt * 64 + wr * 32 + m * 16 + lk * 4;
      #pragma unroll
      for (int i = 0; i < 4; ++i)
        Qo[(size_t)(row0 + i) * D_ + col] = f2bf(acc[m][n][i] + bv);
    }
  }
}

// ---------------------------------------------------------------------------
// gemm_qt: q~[bp,h,:] = Q[bp, h*64..h*64+63] @ wk[h*64.., :]  (K=64)
// T1 XCD swizzle (R22, measured +1us): u = (bid&7)*128 + (bid>>3).
// ---------------------------------------------------------------------------
__global__ __launch_bounds__(256) void gemm_qt(
    const short* __restrict__ Qo, const short* __restrict__ wkT,
    short* __restrict__ Qt)
{
  __shared__ __align__(16) short As[128 * 64];
  __shared__ __align__(16) short Bs[128 * 64];
  const int bid = blockIdx.x;
  const int u = (bid & 7) * 128 + (bid >> 3);
  const int hh = u >> 6, mt = (u >> 3) & 7, nt = u & 7;
  const int tid = threadIdx.x;
  const int wid = tid >> 6, l = tid & 63;
  const int wr = wid >> 1, wc = wid & 1;
  const int lr = l & 15, lk = l >> 4;
  const int sr = l >> 3, scol = (l & 7) * 8;

  #pragma unroll
  for (int j = 0; j < 4; ++j) {
    const int r = (wid * 4 + j) * 8 + sr;
    __builtin_amdgcn_global_load_lds(
        (const __attribute__((address_space(1))) void*)(Qo + (size_t)(mt * 128 + r) * D_ + hh * 64 + scol),
        (__attribute__((address_space(3))) void*)(As + (wid * 4 + j) * 512), 16, 0, 0);
    __builtin_amdgcn_global_load_lds(
        (const __attribute__((address_space(1))) void*)(wkT + (size_t)(nt * 128 + r) * D_ + hh * 64 + scol),
        (__attribute__((address_space(3))) void*)(Bs + (wid * 4 + j) * 512), 16, 0, 0);
  }
  asm volatile("s_waitcnt vmcnt(0)" ::: "memory");
  __syncthreads();

  f32x4 acc[4][4] = {};
  #pragma unroll
  for (int ks = 0; ks < 2; ++ks) {
    short8 a[4], bfr[4];
    #pragma unroll
    for (int m = 0; m < 4; ++m)
      a[m] = *(const short8*)(As + (wr * 64 + m * 16 + lr) * 64 + ks * 32 + lk * 8);
    #pragma unroll
    for (int n = 0; n < 4; ++n)
      bfr[n] = *(const short8*)(Bs + (wc * 64 + n * 16 + lr) * 64 + ks * 32 + lk * 8);
    #pragma unroll
    for (int m = 0; m < 4; ++m)
      #pragma unroll
      for (int n = 0; n < 4; ++n)
        acc[m][n] = __builtin_amdgcn_mfma_f32_16x16x32_bf16(a[m], bfr[n], acc[m][n], 0, 0, 0);
  }

  #pragma unroll
  for (int n = 0; n < 4; ++n) {
    const int col = nt * 128 + wc * 64 + n * 16 + lr;
    #pragma unroll
    for (int m = 0; m < 4; ++m) {
      const int row0 = mt * 128 + wr * 64 + m * 16 + lk * 4;
      #pragma unroll
      for (int i = 0; i < 4; ++i)
        Qt[((size_t)(row0 + i) * 16 + hh) * D_ + col] = f2bf(acc[m][n][i]);
    }
  }
}

// ---------------------------------------------------------------------------
// attn2c: 256 blocks x 4 patches x 512 threads (R23's 2-patch win extended).
// Identical per-patch body to measured-best attn2-v3; sequential loop, full
// state reset, af reloaded per patch, NO cross-patch register prefetch.
// ---------------------------------------------------------------------------
__global__ __launch_bounds__(512) void attn2_kernel(
    const short* __restrict__ Qt, const float* __restrict__ X,
    const int* __restrict__ pos, const float* __restrict__ mask,
    short* __restrict__ Xbar)
{
  __shared__ __align__(16) short Xs[16 * 1024];   // 32KB, swizzled rows of 2048B
  __shared__ float attnT[16][16];                 // [t][h]
  __shared__ float rband[16];
  __shared__ float denL[16];
  __shared__ __align__(16) float red[8][256];     // 8KB reduce tree

  const int bp0 = blockIdx.x * 4;
  const int b = bp0 >> 8;                          // quads never cross batch
  const int tid = threadIdx.x;
  const int w = tid >> 6, l = tid & 63;
  const int t_l = l & 15;
  const int lk = l >> 4;
  const int hgrp = lk * 4;

  const bool is64 = (pos[1] == 0);

  for (int p = 0; p < 4; ++p) {
    const int bp = bp0 + p;

    short8 af[4];
    {
      const short* qb = Qt + ((size_t)bp * 16 + t_l) * D_;
      #pragma unroll
      for (int ks = 0; ks < 4; ++ks)
        af[ks] = *(const short8*)(qb + (w * 4 + ks) * 32 + lk * 8);
    }

    const int start = is64 ? pos[4 * bp]     : pos[2 * bp];
    const int end   = is64 ? pos[4 * bp + 2] : pos[2 * bp + 1];
    const bool valid = (start < S_) && (end <= S_) && (start < end);
    const int lo = valid ? (start < 0 ? 0 : start) : 0;
    const int hi = valid ? end : 0;

    float xacc[16][2];
    #pragma unroll
    for (int h = 0; h < 16; ++h) { xacc[h][0] = 0.f; xacc[h][1] = 0.f; }
    float m_run[4] = {-3.0e38f, -3.0e38f, -3.0e38f, -3.0e38f};
    float den[4] = {0.f, 0.f, 0.f, 0.f};

    for (int c0 = lo; c0 < hi; c0 += 16) {
      __syncthreads();   // guards Xs/attnT/denL reuse across chunks AND patches
      #pragma unroll
      for (int j = 0; j < 16; ++j) {
        int rg = c0 + j; rg = rg < S_ ? rg : S_ - 1;
        const float2 xv = *(const float2*)(X + ((size_t)b * S_ + rg) * D_ + tid * 2);
        short2v o;
        o[0] = f2bf(xv.x); o[1] = f2bf(xv.y);
        *(short2v*)((char*)Xs + j * 2048 + ((tid * 4) ^ ((j & 7) << 4))) = o;
      }
      __syncthreads();

      f32x4 c = {};
      const int rsw = (t_l & 7) << 4;
      #pragma unroll
      for (int ks = 0; ks < 4; ++ks) {
        const int kb = ((w * 4 + ks) * 32 + lk * 8) * 2;
        const short8 x8 = *(const short8*)((char*)Xs + t_l * 2048 + (kb ^ rsw));
        c = __builtin_amdgcn_mfma_f32_16x16x32_bf16(af[ks], x8, c, 0, 0, 0);
      }
      *(f32x4*)&red[w][l * 4] = c;
      __syncthreads();
      f32x4 s = *(const f32x4*)&red[0][l * 4];
      #pragma unroll
      for (int ww = 1; ww < 8; ++ww)
        s = s + *(const f32x4*)&red[ww][l * 4];

      const int tg = c0 + t_l;
      const bool ok = (tg < hi) && (mask[(size_t)b * S_ + tg] != 0.f);
      float wgt[4], rr[4];
      #pragma unroll
      for (int i = 0; i < 4; ++i) {
        const float sc = ok ? s[i] * 0.125f : -3.0e38f;
        float cm = sc;
        cm = fmaxf(cm, __shfl_xor(cm, 1, 64));
        cm = fmaxf(cm, __shfl_xor(cm, 2, 64));
        cm = fmaxf(cm, __shfl_xor(cm, 4, 64));
        cm = fmaxf(cm, __shfl_xor(cm, 8, 64));
        const float nm = fmaxf(m_run[i], cm);
        const float r = __expf(m_run[i] - nm);
        const float wv_ = ok ? __expf(sc - nm) : 0.f;
        float ws = wv_;
        ws += __shfl_xor(ws, 1, 64);
        ws += __shfl_xor(ws, 2, 64);
        ws += __shfl_xor(ws, 4, 64);
        ws += __shfl_xor(ws, 8, 64);
        den[i] = den[i] * r + ws;
        m_run[i] = nm;
        wgt[i] = wv_; rr[i] = r;
      }
      if (w == 0) {
        #pragma unroll
        for (int i = 0; i < 4; ++i) attnT[t_l][hgrp + i] = wgt[i];
        if (t_l == 0) {
          #pragma unroll
          for (int i = 0; i < 4; ++i) rband[hgrp + i] = rr[i];
        }
      }
      __syncthreads();

      #pragma unroll
      for (int h = 0; h < 16; ++h) {
        const float rb = rband[h];
        xacc[h][0] *= rb; xacc[h][1] *= rb;
      }
      #pragma unroll
      for (int t = 0; t < 16; ++t) {
        const f32x4 a0 = *(const f32x4*)&attnT[t][0];
        const f32x4 a1 = *(const f32x4*)&attnT[t][4];
        const f32x4 a2 = *(const f32x4*)&attnT[t][8];
        const f32x4 a3 = *(const f32x4*)&attnT[t][12];
        const short2v xv = *(const short2v*)((char*)Xs + t * 2048 + ((tid * 4) ^ ((t & 7) << 4)));
        const float x0 = b2f(xv[0]), x1 = b2f(xv[1]);
        #pragma unroll
        for (int i = 0; i < 4; ++i) {
          xacc[i][0]      += a0[i] * x0; xacc[i][1]      += a0[i] * x1;
          xacc[i + 4][0]  += a1[i] * x0; xacc[i + 4][1]  += a1[i] * x1;
          xacc[i + 8][0]  += a2[i] * x0; xacc[i + 8][1]  += a2[i] * x1;
          xacc[i + 12][0] += a3[i] * x0; xacc[i + 12][1] += a3[i] * x1;
        }
      }
    }

    __syncthreads();   // prior patch's denL reads done before overwrite
    if (w == 0 && t_l == 0) {
      #pragma unroll
      for (int i = 0; i < 4; ++i) denL[hgrp + i] = den[i];
    }
    __syncthreads();

    bool need = false;
    #pragma unroll
    for (int h = 0; h < 16; ++h) need = need || (denL[h] <= 0.f);
    float ms[2] = {0.f, 0.f};
    if (need) {
      for (int t = 0; t < S_; ++t) {
        const float2 xv = *(const float2*)(X + ((size_t)b * S_ + t) * D_ + tid * 2);
        ms[0] += xv.x; ms[1] += xv.y;
      }
      ms[0] *= (1.f / S_); ms[1] *= (1.f / S_);
    }
    #pragma unroll
    for (int h = 0; h < 16; ++h) {
      const float dL = denL[h];
      short2v o;
      if (dL > 0.f) {
        const float inv = 1.f / dL;
        o[0] = f2bf(xacc[h][0] * inv); o[1] = f2bf(xacc[h][1] * inv);
      } else {
        o[0] = f2bf(ms[0]); o[1] = f2bf(ms[1]);
      }
      *(short2v*)(Xbar + ((size_t)bp * 16 + h) * D_ + tid * 2) = o;
    }
  }
}

// ---------------------------------------------------------------------------
// gemm_v64: AO[:, h*64..] = xbar_h @ wv_h^T + b_v. 256 blocks (16h x 16mt).
// ---------------------------------------------------------------------------
__global__ __launch_bounds__(256) void gemm_v64(
    const short* __restrict__ Xbar, const short* __restrict__ wvb,
    const float* __restrict__ b_v, short* __restrict__ AO)
{
  __shared__ __align__(16) short As[64 * 512];
  __shared__ __align__(16) short Bs[64 * 512];
  const int bid = blockIdx.x;
  const int u = (bid & 7) * 32 + (bid >> 3);
  const int h = u >> 4, mt = u & 15;

  f32x4 acc[2][2] = {};
  gemm64_core(Xbar + (size_t)h * D_, wvb + (size_t)h * 64 * D_,
              mt, 0, D_, 16 * D_, D_, acc, As, Bs);

  const int l = threadIdx.x & 63, w = threadIdx.x >> 6;
  const int wr = w >> 1, wc = w & 1;
  const int lr = l & 15, lk = l >> 4;
  #pragma unroll
  for (int n = 0; n < 2; ++n) {
    const int gcol = h * 64 + wc * 32 + n * 16 + lr;
    const float bv = b_v[gcol];
    #pragma unroll
    for (int m = 0; m < 2; ++m) {
      const int row0 = mt * 64 + wr * 32 + m * 16 + lk * 4;
      #pragma unroll
      for (int i = 0; i < 4; ++i)
        AO[(size_t)(row0 + i) * D_ + gcol] = f2bf(acc[m][n][i] + bv);
    }
  }
}

// O projection + bias + residual, fp32 out. 256 blocks of 64x64.
__global__ __launch_bounds__(256) void gemm_o64(
    const short* __restrict__ AO, const short* __restrict__ wob,
    const float* __restrict__ b_o, const float* __restrict__ pe,
    float* __restrict__ out)
{
  __shared__ __align__(16) short As[64 * 512];
  __shared__ __align__(16) short Bs[64 * 512];
  const int bid = blockIdx.x;
  const int u = (bid & 7) * 32 + (bid >> 3);
  const int mt = u >> 4, nt = u & 15;

  f32x4 acc[2][2] = {};
  gemm64_core(AO, wob, mt, nt, D_, D_, D_, acc, As, Bs);

  const int l = threadIdx.x & 63, w = threadIdx.x >> 6;
  const int wr = w >> 1, wc = w & 1;
  const int lr = l & 15, lk = l >> 4;
  #pragma unroll
  for (int n = 0; n < 2; ++n) {
    const int col = nt * 64 + wc * 32 + n * 16 + lr;
    const float bv = b_o[col];
    #pragma unroll
    for (int m = 0; m < 2; ++m) {
      const int row0 = mt * 64 + wr * 32 + m * 16 + lk * 4;
      #pragma unroll
      for (int i = 0; i < 4; ++i) {
        const size_t idx = (size_t)(row0 + i) * D_ + col;
        out[idx] = acc[m][n][i] + bv + pe[idx];
      }
    }
  }
}

// ---------------------------------------------------------------------------
extern "C" void kernel_launch(void* const* d_in, const int* in_sizes, int n_in,
                              void* d_out, int out_size, void* d_ws, size_t ws_size,
                              hipStream_t stream)
{
  const float* pe    = (const float*)d_in[0];
  const float* xby   = (const float*)d_in[1];
  const int*   pos   = (const int*)d_in[2];
  const float* mask  = (const float*)d_in[3];
  const float* gamma = (const float*)d_in[4];
  const float* beta  = (const float*)d_in[5];
  const float* w_q   = (const float*)d_in[6];
  const float* b_q   = (const float*)d_in[7];
  const float* w_k   = (const float*)d_in[8];
  const float* b_k   = (const float*)d_in[9];  (void)b_k; // softmax-shift invariant
  const float* w_v   = (const float*)d_in[10];
  const float* b_v   = (const float*)d_in[11];
  const float* w_o   = (const float*)d_in[12];
  const float* b_o   = (const float*)d_in[13];

  char* ws = (char*)d_ws;
  short* Qt   = (short*)(ws);                // 32 MB: q~ [bp*16+h][1024] bf16
  short* Xbar = (short*)(ws + 33554432);     // 32 MB: xbar same layout
  short* wqb  = (short*)(ws + 67108864);     // 2 MB each
  short* wvb  = (short*)(ws + 69206016);
  short* wob  = (short*)(ws + 71303168);
  short* wkT  = (short*)(ws + 73400320);     // 2 MB: wk transposed bf16
  short* qx   = (short*)(ws + 75497472);     // 2 MB: LN(pe) bf16
  short* Qo   = (short*)(ws + 77594624);     // 2 MB: Q bf16
  short* AO   = (short*)(ws + 79691776);     // 2 MB: attention out bf16
  (void)in_sizes; (void)n_in; (void)out_size; (void)ws_size;

  prep2_kernel<<<2624, 256, 0, stream>>>(pe, gamma, beta, w_q, w_k, w_v, w_o,
                                         wqb, wvb, wob, wkT, qx);
  gemm_q64<<<256, 256, 0, stream>>>(qx, wqb, b_q, Qo);
  gemm_qt<<<1024, 256, 0, stream>>>(Qo, wkT, Qt);
  attn2_kernel<<<256, 512, 0, stream>>>(Qt, xby, pos, mask, Xbar);
  gemm_v64<<<256, 256, 0, stream>>>(Xbar, wvb, b_v, AO);
  gemm_o64<<<256, 256, 0, stream>>>(AO, wob, b_o, pe, (float*)d_out);
}